// Round 4
// baseline (340.682 us; speedup 1.0000x reference)
//
#include <hip/hip_runtime.h>
#include <math.h>

#define BB 128
#define EE 64
#define TT 2048
#define C2 32
#define W1 2049
#define WPW 512
#define CH 33
#define FEAT 4096
#define NBLK (9 * 128)

// workspace float offsets
#define OFF_X2   ((size_t)0)                      // 128*32*2048 = 8388608
#define OFF_PSUM ((size_t)8388608)                // 32*1152
#define OFF_PSQ  ((size_t)8425472)                // 32*1152
#define OFF_SS   ((size_t)8462336)                // 64
#define OFF_Y    ((size_t)8462400)                // 128*32*512 = 2097152
#define OFF_ZZ   ((size_t)10559552)               // 512*128*32 = 2097152
#define OFF_QSQ  ((size_t)12656704)               // 128*128
#define OFF_TNEW ((size_t)12673088)               // 128
#define OFF_PREP ((size_t)12673216)               // 16

// ---- fused: P (registers/LDS only) + conv1 + sign(bn1_gamma) + x2 + bn2 partial stats ----
__global__ __launch_bounds__(256) void k_px(
        const float* __restrict__ in, const float* __restrict__ w2,
        const float* __restrict__ w1, const float* __restrict__ g1,
        float* __restrict__ x2, float* __restrict__ psum, float* __restrict__ psq) {
    int bx = blockIdx.x;            // 0..8, w0 = bx*256
    int b  = blockIdx.y;
    int w0 = bx * 256;
    int tid = threadIdx.x;          // 256
    __shared__ float lw2[C2][EE];   // 8 KB
    __shared__ float lp[C2][288];   // 36.9 KB  (P tile, cols t = w0-16 .. w0+270)
    __shared__ float lw1[16][32];   // conv1 weights with sign(g1) folded in
    __shared__ float lds_s[C2], lds_q[C2];
    for (int j = tid; j < 2048; j += 256) lw2[j >> 6][j & 63] = w2[j];
    for (int j = tid; j < 512; j += 256) {
        int g = j >> 5;
        float sgn = (g1[g] < 0.f) ? -1.f : 1.f;
        lw1[g][j & 31] = w1[j] * sgn;
    }
    __syncthreads();
    // ---- P phase: each thread computes full c-column(s) of P ----
    const float* ib = in + (size_t)b * EE * TT;
    for (int col = tid; col < 287; col += 256) {
        int t = w0 - 16 + col;
        float acc[C2];
#pragma unroll
        for (int c = 0; c < C2; c++) acc[c] = 0.f;
        if (t >= 0 && t < TT) {
            for (int e = 0; e < EE; e++) {
                float v = ib[e * TT + t];
#pragma unroll
                for (int c = 0; c < C2; c++) acc[c] = fmaf(lw2[c][e], v, acc[c]);
            }
        }
#pragma unroll
        for (int c = 0; c < C2; c++) lp[c][col] = acc[c];
    }
    __syncthreads();
    // ---- conv phase: 8 rounds, wave-uniform c, 4 w per thread ----
    for (int r = 0; r < 8; r++) {
        int task = r * 256 + tid;
        int c = task >> 6;          // uniform across each wave
        int wq = task & 63;
        int wbase = wq * 4;
        float win[36];
#pragma unroll
        for (int i = 0; i < 9; i++) {
            float4 v4 = *(const float4*)&lp[c][wbase + i * 4];
            win[i * 4 + 0] = v4.x; win[i * 4 + 1] = v4.y;
            win[i * 4 + 2] = v4.z; win[i * 4 + 3] = v4.w;
        }
        const float* wc = lw1[c >> 1];
        float ls = 0.f, lq = 0.f;
        float* xrow = x2 + ((size_t)b * C2 + c) * (size_t)TT + w0;
#pragma unroll
        for (int i = 0; i < 4; i++) {
            float acc = 0.f;
#pragma unroll
            for (int k = 0; k < 32; k++) acc = fmaf(wc[k], win[i + k], acc);
            int w = w0 + wbase + i;
            if (w < W1) { ls += acc; lq = fmaf(acc, acc, lq); }
            if (w < TT) xrow[wbase + i] = acc;
        }
#pragma unroll
        for (int d = 1; d < 64; d <<= 1) {
            ls += __shfl_xor(ls, d);
            lq += __shfl_xor(lq, d);
        }
        if ((tid & 63) == 0) { lds_s[c] = ls; lds_q[c] = lq; }  // (r,wave)->c bijective
    }
    __syncthreads();
    if (tid < C2) {
        int blk = b * 9 + bx;
        psum[tid * NBLK + blk] = lds_s[tid];
        psq[tid * NBLK + blk]  = lds_q[tid];
    }
}

__global__ __launch_bounds__(512) void k_bn2fin(
        const float* __restrict__ psum, const float* __restrict__ psq,
        const float* __restrict__ gamma, const float* __restrict__ beta,
        float* __restrict__ ss) {
    int tid = threadIdx.x;          // 512
    int c = tid >> 4, l = tid & 15;
    float s = 0.f, q = 0.f;
    for (int j = l; j < NBLK; j += 16) {
        s += psum[c * NBLK + j];
        q += psq[c * NBLK + j];
    }
#pragma unroll
    for (int d = 1; d < 16; d <<= 1) { s += __shfl_xor(s, d); q += __shfl_xor(q, d); }
    if (l == 0) {
        float n = (float)(BB * W1);
        float m = s / n;
        float var = q / n - m * m;
        float sc = gamma[c] * rsqrtf(var + 1e-3f);
        ss[c] = sc;
        ss[32 + c] = beta[c] - m * sc;
    }
}

// ---- elementwise: bn2 + elu + avgpool4 ----
__global__ __launch_bounds__(256) void k_pool2(
        const float* __restrict__ x2, const float* __restrict__ ss,
        float* __restrict__ y) {
    int idx = blockIdx.x * 256 + threadIdx.x;    // over 128*32*512
    int wp = idx & 511;
    int bc = idx >> 9;
    int c = bc & 31;
    float4 v = *(const float4*)(x2 + (size_t)bc * TT + wp * 4);
    float sc = ss[c], sh = ss[32 + c];
    float s = 0.f, a;
    a = fmaf(sc, v.x, sh); s += (a > 0.f) ? a : expm1f(a);
    a = fmaf(sc, v.y, sh); s += (a > 0.f) ? a : expm1f(a);
    a = fmaf(sc, v.z, sh); s += (a > 0.f) ? a : expm1f(a);
    a = fmaf(sc, v.w, sh); s += (a > 0.f) ? a : expm1f(a);
    y[idx] = s * 0.25f;
}

// ---- zz[w][b][c] = sum_k ew[c,k]*y[b,c,w-8+k], w<512 only ----
__global__ __launch_bounds__(256) void k_ec1(
        const float* __restrict__ y, const float* __restrict__ ew,
        float* __restrict__ zz) {
    int b = blockIdx.y;
    int w0 = blockIdx.x * 8;        // 64 tiles -> w<512
    int c = threadIdx.x & 31, wl = threadIdx.x >> 5;
    __shared__ float ly[32][25];
    __shared__ float lew[32][16];
    const float* yb = y + (size_t)b * C2 * WPW;
    for (int j = threadIdx.x; j < 32 * 23; j += 256) {
        int cc = j / 23, tt = j % 23;
        int t = w0 - 8 + tt;
        ly[cc][tt] = (t >= 0 && t < WPW) ? yb[cc * WPW + t] : 0.f;
    }
    for (int j = threadIdx.x; j < 512; j += 256) lew[j >> 4][j & 15] = ew[j];
    __syncthreads();
    int w = w0 + wl;
    float acc = 0.f;
#pragma unroll
    for (int k = 0; k < 16; k++) acc = fmaf(lew[c][k], ly[c][wl + k], acc);
    zz[((size_t)w * BB + b) * C2 + c] = acc;
}

// ---- fused: normalize + lc1 matvec + lorentz_bn + elu + lorentz pool + flatten ----
__global__ __launch_bounds__(512) void k_tail(
        const float* __restrict__ zz, const float* __restrict__ lc1,
        const float* __restrict__ bs, float* __restrict__ outp,
        float* __restrict__ qsq) {
    int wp = blockIdx.x;            // 0..127
    int tid = threadIdx.x;          // 512
    int j = tid >> 7;               // w offset 0..3
    int b = tid & 127;
    int w = wp * 4 + j;
    __shared__ float lw[1089];
    __shared__ float wsum[4][2][33];
    __shared__ float vred[4][2];
    __shared__ float lavg[128][33];
    for (int i = tid; i < 1089; i += 512) lw[i] = lc1[i];
    float* lz = &lavg[0][0];
    for (int i = tid; i < 128 * 33; i += 512) lz[i] = 0.f;
    __syncthreads();
    // ---- head: L2-normalize, add_time, clamp, 33x33 matvec, add_time ----
    float x[33];
    {
        float xin[32];
        float ssq = 0.f;
        const float* zp = zz + ((size_t)w * BB + b) * C2;
#pragma unroll
        for (int i = 0; i < 32; i += 4) {
            float4 v = *(const float4*)(zp + i);
            xin[i] = v.x; xin[i + 1] = v.y; xin[i + 2] = v.z; xin[i + 3] = v.w;
        }
#pragma unroll
        for (int i = 0; i < 32; i++) ssq = fmaf(xin[i], xin[i], ssq);
        float inv = 1.f / (sqrtf(ssq) + 1e-8f);
        float s2 = 0.f;
#pragma unroll
        for (int i = 0; i < 32; i++) { xin[i] *= inv; s2 = fmaf(xin[i], xin[i], s2); }
        float t = sqrtf(1.f + s2);
        float pre0 = fmaxf(t, 1.f);
        float sy = 0.f;
        for (int o = 1; o < 33; o++) {
            const float* wr = lw + o * 33;
            float a = wr[0] * pre0;
#pragma unroll
            for (int i = 0; i < 32; i++) a = fmaf(wr[1 + i], xin[i], a);
            x[o] = a;
            sy = fmaf(a, a, sy);
        }
        x[0] = sqrtf(1.f + sy);
    }
    // ---- lorentz_bn over b (per w-group of 2 waves) ----
    float mu[33];
#pragma unroll
    for (int ch = 0; ch < 33; ch++) {
        float s = x[ch];
        s += __shfl_xor(s, 1);  s += __shfl_xor(s, 2);  s += __shfl_xor(s, 4);
        s += __shfl_xor(s, 8);  s += __shfl_xor(s, 16); s += __shfl_xor(s, 32);
        mu[ch] = s;
    }
    int wv = b >> 6;
    if ((b & 63) == 0) {
#pragma unroll
        for (int ch = 0; ch < 33; ch++) wsum[j][wv][ch] = mu[ch];
    }
    __syncthreads();
#pragma unroll
    for (int ch = 0; ch < 33; ch++) mu[ch] = (wsum[j][0][ch] + wsum[j][1][ch]) * (1.f / 128.f);
    float a0 = mu[0], sp = 0.f;
#pragma unroll
    for (int i = 1; i < 33; i++) sp = fmaf(mu[i], mu[i], sp);
    float rd = rsqrtf(fmaxf(a0 * a0 - sp, 1e-8f));
#pragma unroll
    for (int ch = 0; ch < 33; ch++) mu[ch] *= rd;
    float xin = x[0] * mu[0];
#pragma unroll
    for (int i = 1; i < 33; i++) xin -= x[i] * mu[i];
    float dist = acoshf(fmaxf(xin, 1.f + 1e-7f));
    float dq = dist * dist;
    dq += __shfl_xor(dq, 1);  dq += __shfl_xor(dq, 2);  dq += __shfl_xor(dq, 4);
    dq += __shfl_xor(dq, 8);  dq += __shfl_xor(dq, 16); dq += __shfl_xor(dq, 32);
    if ((b & 63) == 0) vred[j][wv] = dq;
    __syncthreads();
    float var = (vred[j][0] + vred[j][1]) * (1.f / 128.f);
#pragma unroll
    for (int ch = 0; ch < 33; ch++) x[ch] = x[ch] - xin * mu[ch];   // u
    float lu = -x[0] * x[0];
#pragma unroll
    for (int i = 1; i < 33; i++) lu = fmaf(x[i], x[i], lu);
    float f = dist * rsqrtf(fmaxf(lu, 1e-8f));
#pragma unroll
    for (int ch = 0; ch < 33; ch++) x[ch] *= f;                     // v
    float corr = -x[0] / (1.f + mu[0]);
    x[0] += corr * (mu[0] + 1.f);
#pragma unroll
    for (int i = 1; i < 33; i++) x[i] = fmaf(corr, mu[i], x[i]);
    float scb = bs[w] * rsqrtf(var + 1e-5f);
#pragma unroll
    for (int ch = 0; ch < 33; ch++) x[ch] *= scb;
    float nn = -x[0] * x[0];
#pragma unroll
    for (int i = 1; i < 33; i++) nn = fmaf(x[i], x[i], nn);
    float n = sqrtf(fmaxf(nn, 1e-9f));
    float shn = sinhf(n) / n;
    float sg = 0.f;
#pragma unroll
    for (int i = 1; i < 33; i++) {
        float e = shn * x[i];
        e = (e > 0.f) ? e : expm1f(e);
        x[i] = e;
        sg = fmaf(e, e, sg);
    }
    x[0] = sqrtf(1.f + sg);
    // ---- lorentz avgpool over the 4 w in this block + flatten ----
    for (int jj = 0; jj < 4; jj++) {
        if (j == jj) {
#pragma unroll
            for (int ch = 0; ch < 33; ch++) lavg[b][ch] += x[ch];
        }
        __syncthreads();
    }
    if (tid < 128) {
        int bb2 = tid;
        float avg[33];
#pragma unroll
        for (int ch = 0; ch < 33; ch++) avg[ch] = lavg[bb2][ch] * 0.25f;
        float sp2 = 0.f;
#pragma unroll
        for (int i = 1; i < 33; i++) sp2 = fmaf(avg[i], avg[i], sp2);
        float l = avg[0] * avg[0] - sp2;
        float rd2 = rsqrtf(fmaxf(l, 1e-8f));
        float q0 = avg[0] * rd2;
        float* fb = outp + 512 + (size_t)bb2 * 4097;
#pragma unroll
        for (int i = 1; i < 33; i++) fb[1 + wp * 32 + (i - 1)] = avg[i] * rd2;
        qsq[wp * 128 + bb2] = q0 * q0;
    }
}

__global__ __launch_bounds__(128) void k_fin(
        const float* __restrict__ qsq, float* __restrict__ outp,
        float* __restrict__ tnew) {
    int b = threadIdx.x;            // 128
    float s = 0.f;
    for (int wp = 0; wp < 128; wp++) s += qsq[wp * 128 + b];
    float tn = sqrtf(fmaxf(s - 127.f, 1e-8f));
    outp[512 + (size_t)b * 4097] = tn;
    tnew[b] = tn;
}

__global__ __launch_bounds__(256) void k_mlrprep(
        const float* __restrict__ z, const float* __restrict__ a,
        float* __restrict__ prep) {
    __shared__ float red[256];
    for (int c = 0; c < 4; c++) {
        float s = 0.f;
        for (int j = threadIdx.x; j < FEAT; j += 256) {
            float v = z[c * FEAT + j];
            s = fmaf(v, v, s);
        }
        red[threadIdx.x] = s;
        __syncthreads();
        for (int st = 128; st > 0; st >>= 1) {
            if (threadIdx.x < st) red[threadIdx.x] += red[threadIdx.x + st];
            __syncthreads();
        }
        if (threadIdx.x == 0) {
            float nz = sqrtf(red[0]);
            float ca = coshf(a[c]), sa = sinhf(a[c]);
            float wt = sa * nz;
            float cb = ca * nz;
            float bb = sqrtf(fmaxf(cb * cb - wt * wt, 1e-8f));
            prep[c] = wt;
            prep[4 + c] = bb;
            prep[8 + c] = ca;
        }
        __syncthreads();
    }
}

__global__ __launch_bounds__(256) void k_mlr(
        const float* __restrict__ out_feats, const float* __restrict__ tnew,
        const float* __restrict__ z, const float* __restrict__ prep,
        float* __restrict__ logits) {
    int b = blockIdx.x;
    __shared__ float red[256];
    const float* fs = out_feats + (size_t)b * 4097 + 1;
    for (int c = 0; c < 4; c++) {
        float s = 0.f;
        for (int j = threadIdx.x; j < FEAT; j += 256) s = fmaf(fs[j], z[c * FEAT + j], s);
        red[threadIdx.x] = s;
        __syncthreads();
        for (int st = 128; st > 0; st >>= 1) {
            if (threadIdx.x < st) red[threadIdx.x] += red[threadIdx.x + st];
            __syncthreads();
        }
        if (threadIdx.x == 0) {
            float alpha = -tnew[b] * prep[c] + prep[8 + c] * red[0];
            float bb = prep[4 + c];
            float d = fabsf(asinhf(alpha / bb));
            float sg = (alpha > 0.f) ? 1.f : ((alpha < 0.f) ? -1.f : 0.f);
            logits[b * 4 + c] = sg * bb * d;
        }
        __syncthreads();
    }
}

extern "C" void kernel_launch(void* const* d_in, const int* in_sizes, int n_in,
                              void* d_out, int out_size, void* d_ws, size_t ws_size,
                              hipStream_t stream) {
    const float* in   = (const float*)d_in[0];
    const float* w1   = (const float*)d_in[2];   // conv1_w (16,1,1,32)
    const float* g1   = (const float*)d_in[3];   // bn1_gamma (only sign matters)
    const float* w2   = (const float*)d_in[5];   // conv2_w (32,1,64,1)
    const float* g2   = (const float*)d_in[6];
    const float* b2   = (const float*)d_in[7];
    const float* ew   = (const float*)d_in[8];   // ec1_w (32,1,1,16)
    const float* lc1  = (const float*)d_in[9];   // (33,33)
    const float* bs   = (const float*)d_in[10];  // bn_s (513)
    const float* mlra = (const float*)d_in[11];  // (4,)
    const float* mlrz = (const float*)d_in[12];  // (4,4096)
    float* out = (float*)d_out;
    float* ws = (float*)d_ws;

    float* X2   = ws + OFF_X2;
    float* PSUM = ws + OFF_PSUM;
    float* PSQ  = ws + OFF_PSQ;
    float* SS   = ws + OFF_SS;
    float* Y    = ws + OFF_Y;
    float* ZZ   = ws + OFF_ZZ;
    float* QSQ  = ws + OFF_QSQ;
    float* TN   = ws + OFF_TNEW;
    float* PREP = ws + OFF_PREP;

    k_px<<<dim3(9, 128), 256, 0, stream>>>(in, w2, w1, g1, X2, PSUM, PSQ);
    k_bn2fin<<<1, 512, 0, stream>>>(PSUM, PSQ, g2, b2, SS);
    k_pool2<<<(BB * C2 * WPW) / 256, 256, 0, stream>>>(X2, SS, Y);
    k_ec1<<<dim3(64, 128), 256, 0, stream>>>(Y, ew, ZZ);
    k_tail<<<128, 512, 0, stream>>>(ZZ, lc1, bs, out, QSQ);
    k_fin<<<1, 128, 0, stream>>>(QSQ, out, TN);
    k_mlrprep<<<1, 256, 0, stream>>>(mlrz, mlra, PREP);
    k_mlr<<<128, 256, 0, stream>>>(out + 512, TN, mlrz, PREP, out);
}

// Round 5
// 211.118 us; speedup vs baseline: 1.6137x; 1.6137x over previous
//
#include <hip/hip_runtime.h>
#include <math.h>

#define BB 128
#define EE 64
#define TT 2048
#define C2 32
#define W1 2049
#define WPW 512
#define FEAT 4096
#define NBLK 1024

// float offsets in ws
#define OFF_P    ((size_t)0)          // bf16 P: 128*32*2048 ushort = 4,194,304 floats
#define OFF_X2   ((size_t)4194304)    // bf16 X2: 4,194,304 floats
#define OFF_PSUM ((size_t)8388608)    // 32*1024
#define OFF_PSQ  ((size_t)8421376)    // 32*1024
#define OFF_SS   ((size_t)8454144)    // 64
#define OFF_Y    ((size_t)8454208)    // bf16 Y: 128*32*512 ushort = 1,048,576 floats
#define OFF_ZZ   ((size_t)9502784)    // fp32 [512][128][32] = 2,097,152
#define OFF_QSQ  ((size_t)11599936)   // 128*128

__device__ __forceinline__ unsigned short f2b(float f) {
    unsigned int u = __float_as_uint(f);
    u += 0x7FFFu + ((u >> 16) & 1u);
    return (unsigned short)(u >> 16);
}
__device__ __forceinline__ float b2f(unsigned short s) {
    return __uint_as_float(((unsigned int)s) << 16);
}

// ---- P[b,c,t] = sum_e w2[c,e]*in[b,e,t], stored bf16 ----
__global__ __launch_bounds__(256) void k_p(const float* __restrict__ in,
        const float* __restrict__ w2, unsigned short* __restrict__ P) {
    int b = blockIdx.y, t0 = blockIdx.x * 256, tid = threadIdx.x;
    __shared__ unsigned short li[64][256];   // 32 KB bf16 input tile
    __shared__ float lw2s[32][64];           // 8 KB
    const float* ib = in + (size_t)b * EE * TT + t0;
    for (int j = tid; j < 64 * 64; j += 256) {
        int e = j >> 6, q = j & 63;
        float4 v = *(const float4*)(ib + e * TT + q * 4);
        li[e][q * 4 + 0] = f2b(v.x); li[e][q * 4 + 1] = f2b(v.y);
        li[e][q * 4 + 2] = f2b(v.z); li[e][q * 4 + 3] = f2b(v.w);
    }
    for (int j = tid; j < 2048; j += 256) lw2s[j >> 6][j & 63] = w2[j];
    __syncthreads();
    int cg = tid >> 6, colg = tid & 63;
    int c8 = cg * 8;
    float acc[4][8];
#pragma unroll
    for (int x = 0; x < 4; x++)
#pragma unroll
        for (int jj = 0; jj < 8; jj++) acc[x][jj] = 0.f;
    for (int e = 0; e < 64; e += 2) {
        uint2 r0 = *(const uint2*)&li[e][colg * 4];
        uint2 r1 = *(const uint2*)&li[e + 1][colg * 4];
        float v0[4], v1[4];
        v0[0] = __uint_as_float(r0.x << 16); v0[1] = __uint_as_float(r0.x & 0xFFFF0000u);
        v0[2] = __uint_as_float(r0.y << 16); v0[3] = __uint_as_float(r0.y & 0xFFFF0000u);
        v1[0] = __uint_as_float(r1.x << 16); v1[1] = __uint_as_float(r1.x & 0xFFFF0000u);
        v1[2] = __uint_as_float(r1.y << 16); v1[3] = __uint_as_float(r1.y & 0xFFFF0000u);
#pragma unroll
        for (int jj = 0; jj < 8; jj++) {
            float2 wv = *(const float2*)&lw2s[c8 + jj][e];
#pragma unroll
            for (int x = 0; x < 4; x++) {
                acc[x][jj] = fmaf(wv.x, v0[x], acc[x][jj]);
                acc[x][jj] = fmaf(wv.y, v1[x], acc[x][jj]);
            }
        }
    }
    unsigned short* Pb = P + (size_t)b * C2 * TT + t0 + colg * 4;
#pragma unroll
    for (int jj = 0; jj < 8; jj++) {
        int c = c8 + jj;
        uint2 o;
        o.x = (unsigned int)f2b(acc[0][jj]) | ((unsigned int)f2b(acc[1][jj]) << 16);
        o.y = (unsigned int)f2b(acc[2][jj]) | ((unsigned int)f2b(acc[3][jj]) << 16);
        *(uint2*)(Pb + (size_t)c * TT) = o;
    }
}

// ---- conv1(32 taps) + sign(bn1_gamma) + X2(bf16) + bn2 partial stats ----
__global__ __launch_bounds__(256) void k_cs(const unsigned short* __restrict__ P,
        const float* __restrict__ w1, const float* __restrict__ g1,
        unsigned short* __restrict__ x2, float* __restrict__ psum, float* __restrict__ psq) {
    int bx = blockIdx.x, b = blockIdx.y, w0 = bx * 256, tid = threadIdx.x;
    __shared__ unsigned short lp[32][288];   // 18 KB
    __shared__ float lw1[16][32];
    __shared__ float lds_s[32], lds_q[32];
    const unsigned short* Pb = P + (size_t)b * C2 * TT;
    for (int j = tid; j < 32 * 72; j += 256) {
        int c = j / 72, g4 = j % 72;
        int t = w0 - 16 + g4 * 4;
        uint2 v = make_uint2(0u, 0u);
        if (t >= 0 && t + 3 < TT) v = *(const uint2*)(Pb + (size_t)c * TT + t);
        *(uint2*)&lp[c][g4 * 4] = v;
    }
    for (int j = tid; j < 512; j += 256) {
        int g = j >> 5;
        float sgn = (g1[g] < 0.f) ? -1.f : 1.f;
        lw1[g][j & 31] = w1[j] * sgn;
    }
    __syncthreads();
    for (int r = 0; r < 8; r++) {
        int task = r * 256 + tid;
        int c = task >> 6;          // wave-uniform
        int wq = task & 63;
        int wbase = wq * 4;
        float win[36];
#pragma unroll
        for (int i = 0; i < 9; i++) {
            uint2 v = *(const uint2*)&lp[c][wbase + i * 4];
            win[i * 4 + 0] = __uint_as_float(v.x << 16);
            win[i * 4 + 1] = __uint_as_float(v.x & 0xFFFF0000u);
            win[i * 4 + 2] = __uint_as_float(v.y << 16);
            win[i * 4 + 3] = __uint_as_float(v.y & 0xFFFF0000u);
        }
        const float* wc = lw1[c >> 1];
        float ls = 0.f, lq = 0.f;
        float accs[4];
#pragma unroll
        for (int i = 0; i < 4; i++) {
            float acc = 0.f;
#pragma unroll
            for (int k = 0; k < 32; k++) acc = fmaf(wc[k], win[i + k], acc);
            accs[i] = acc;
            ls += acc; lq = fmaf(acc, acc, lq);
        }
        uint2 o;
        o.x = (unsigned int)f2b(accs[0]) | ((unsigned int)f2b(accs[1]) << 16);
        o.y = (unsigned int)f2b(accs[2]) | ((unsigned int)f2b(accs[3]) << 16);
        *(uint2*)(x2 + ((size_t)b * C2 + c) * TT + w0 + wbase) = o;
#pragma unroll
        for (int d = 1; d < 64; d <<= 1) {
            ls += __shfl_xor(ls, d);
            lq += __shfl_xor(lq, d);
        }
        if ((tid & 63) == 0) { lds_s[c] = ls; lds_q[c] = lq; }
    }
    __syncthreads();
    if (bx == 7 && tid < 32) {      // stats for w=2048 (taps k<=15 valid)
        const float* wc = lw1[tid >> 1];
        float acc = 0.f;
#pragma unroll
        for (int k = 0; k < 16; k++) acc = fmaf(wc[k], b2f(lp[tid][256 + k]), acc);
        lds_s[tid] += acc;
        lds_q[tid] += acc * acc;
    }
    __syncthreads();
    if (tid < 32) {
        int blk = b * 8 + bx;
        psum[tid * NBLK + blk] = lds_s[tid];
        psq[tid * NBLK + blk]  = lds_q[tid];
    }
}

__global__ __launch_bounds__(64) void k_bn2fin(
        const float* __restrict__ psum, const float* __restrict__ psq,
        const float* __restrict__ gamma, const float* __restrict__ beta,
        float* __restrict__ ss) {
    int c = blockIdx.x, l = threadIdx.x;
    float s = 0.f, q = 0.f;
    for (int j = l; j < NBLK; j += 64) { s += psum[c * NBLK + j]; q += psq[c * NBLK + j]; }
#pragma unroll
    for (int d = 1; d < 64; d <<= 1) { s += __shfl_xor(s, d); q += __shfl_xor(q, d); }
    if (l == 0) {
        float n = (float)(BB * W1);
        float m = s / n;
        float var = q / n - m * m;
        float sc = gamma[c] * rsqrtf(var + 1e-3f);
        ss[c] = sc;
        ss[32 + c] = beta[c] - m * sc;
    }
}

// ---- bn2 + elu + avgpool4 : X2 bf16 -> Y bf16 ----
__global__ __launch_bounds__(256) void k_pool2(
        const unsigned short* __restrict__ x2, const float* __restrict__ ss,
        unsigned short* __restrict__ y) {
    int idx = blockIdx.x * 256 + threadIdx.x;
    int wp = idx & 511;
    int bc = idx >> 9;
    int c = bc & 31;
    uint2 v = *(const uint2*)(x2 + (size_t)bc * TT + wp * 4);
    float sc = ss[c], sh = ss[32 + c];
    float a, s = 0.f;
    a = fmaf(sc, __uint_as_float(v.x << 16), sh);        s += (a > 0.f) ? a : expm1f(a);
    a = fmaf(sc, __uint_as_float(v.x & 0xFFFF0000u), sh); s += (a > 0.f) ? a : expm1f(a);
    a = fmaf(sc, __uint_as_float(v.y << 16), sh);        s += (a > 0.f) ? a : expm1f(a);
    a = fmaf(sc, __uint_as_float(v.y & 0xFFFF0000u), sh); s += (a > 0.f) ? a : expm1f(a);
    y[idx] = f2b(s * 0.25f);
}

// ---- zz[w][b][c] = sum_k ew[c,k]*y[b,c,w-8+k], w<512, fp32 out ----
__global__ __launch_bounds__(256) void k_ec1(
        const unsigned short* __restrict__ y, const float* __restrict__ ew,
        float* __restrict__ zz) {
    int b = blockIdx.y, w0 = blockIdx.x * 64;
    int tid = threadIdx.x, c = tid & 31, wl = tid >> 5;   // wl 0..7
    __shared__ unsigned short ly[32][84];   // cols t=w0-8 .. w0+71 (pad 84 for banks)
    __shared__ float lew[32][16];
    const unsigned short* yb = y + (size_t)b * C2 * WPW;
    for (int j = tid; j < 32 * 20; j += 256) {
        int cc = j / 20, g4 = j % 20;
        int t = w0 - 8 + g4 * 4;
        uint2 v = make_uint2(0u, 0u);
        if (t >= 0 && t + 3 < WPW) v = *(const uint2*)(yb + (size_t)cc * WPW + t);
        *(uint2*)&ly[cc][g4 * 4] = v;
    }
    for (int j = tid; j < 512; j += 256) lew[j >> 4][j & 15] = ew[j];
    __syncthreads();
    float win[24];
#pragma unroll
    for (int i = 0; i < 6; i++) {
        uint2 v = *(const uint2*)&ly[c][wl * 8 + i * 4];
        win[i * 4 + 0] = __uint_as_float(v.x << 16);
        win[i * 4 + 1] = __uint_as_float(v.x & 0xFFFF0000u);
        win[i * 4 + 2] = __uint_as_float(v.y << 16);
        win[i * 4 + 3] = __uint_as_float(v.y & 0xFFFF0000u);
    }
    const float* wc = lew[c];
#pragma unroll
    for (int i = 0; i < 8; i++) {
        float acc = 0.f;
#pragma unroll
        for (int k = 0; k < 16; k++) acc = fmaf(wc[k], win[i + k], acc);
        zz[((size_t)(w0 + wl * 8 + i) * BB + b) * C2 + c] = acc;
    }
}

// ---- fused: normalize + lc1 matvec + lorentz_bn + elu + lorentz pool + flatten ----
__global__ __launch_bounds__(512) void k_tail(
        const float* __restrict__ zz, const float* __restrict__ lc1,
        const float* __restrict__ bs, float* __restrict__ outp,
        float* __restrict__ qsq) {
    int wp = blockIdx.x;            // 0..127
    int tid = threadIdx.x;          // 512
    int j = tid >> 7;               // w offset 0..3
    int b = tid & 127;
    int w = wp * 4 + j;
    __shared__ float lw[1089];
    __shared__ float wsum[4][2][33];
    __shared__ float vred[4][2];
    __shared__ float lavg[128][33];
    for (int i = tid; i < 1089; i += 512) lw[i] = lc1[i];
    float* lz = &lavg[0][0];
    for (int i = tid; i < 128 * 33; i += 512) lz[i] = 0.f;
    __syncthreads();
    float x[33];
    {
        float xin[32];
        float ssq = 0.f;
        const float* zp = zz + ((size_t)w * BB + b) * C2;
#pragma unroll
        for (int i = 0; i < 32; i += 4) {
            float4 v = *(const float4*)(zp + i);
            xin[i] = v.x; xin[i + 1] = v.y; xin[i + 2] = v.z; xin[i + 3] = v.w;
        }
#pragma unroll
        for (int i = 0; i < 32; i++) ssq = fmaf(xin[i], xin[i], ssq);
        float inv = 1.f / (sqrtf(ssq) + 1e-8f);
        float s2 = 0.f;
#pragma unroll
        for (int i = 0; i < 32; i++) { xin[i] *= inv; s2 = fmaf(xin[i], xin[i], s2); }
        float t = sqrtf(1.f + s2);
        float pre0 = fmaxf(t, 1.f);
        float sy = 0.f;
        for (int o = 1; o < 33; o++) {
            const float* wr = lw + o * 33;
            float a = wr[0] * pre0;
#pragma unroll
            for (int i = 0; i < 32; i++) a = fmaf(wr[1 + i], xin[i], a);
            x[o] = a;
            sy = fmaf(a, a, sy);
        }
        x[0] = sqrtf(1.f + sy);
    }
    float mu[33];
#pragma unroll
    for (int ch = 0; ch < 33; ch++) {
        float s = x[ch];
        s += __shfl_xor(s, 1);  s += __shfl_xor(s, 2);  s += __shfl_xor(s, 4);
        s += __shfl_xor(s, 8);  s += __shfl_xor(s, 16); s += __shfl_xor(s, 32);
        mu[ch] = s;
    }
    int wv = b >> 6;
    if ((b & 63) == 0) {
#pragma unroll
        for (int ch = 0; ch < 33; ch++) wsum[j][wv][ch] = mu[ch];
    }
    __syncthreads();
#pragma unroll
    for (int ch = 0; ch < 33; ch++) mu[ch] = (wsum[j][0][ch] + wsum[j][1][ch]) * (1.f / 128.f);
    float a0 = mu[0], sp = 0.f;
#pragma unroll
    for (int i = 1; i < 33; i++) sp = fmaf(mu[i], mu[i], sp);
    float rd = rsqrtf(fmaxf(a0 * a0 - sp, 1e-8f));
#pragma unroll
    for (int ch = 0; ch < 33; ch++) mu[ch] *= rd;
    float xin = x[0] * mu[0];
#pragma unroll
    for (int i = 1; i < 33; i++) xin -= x[i] * mu[i];
    float dist = acoshf(fmaxf(xin, 1.f + 1e-7f));
    float dq = dist * dist;
    dq += __shfl_xor(dq, 1);  dq += __shfl_xor(dq, 2);  dq += __shfl_xor(dq, 4);
    dq += __shfl_xor(dq, 8);  dq += __shfl_xor(dq, 16); dq += __shfl_xor(dq, 32);
    if ((b & 63) == 0) vred[j][wv] = dq;
    __syncthreads();
    float var = (vred[j][0] + vred[j][1]) * (1.f / 128.f);
#pragma unroll
    for (int ch = 0; ch < 33; ch++) x[ch] = x[ch] - xin * mu[ch];
    float lu = -x[0] * x[0];
#pragma unroll
    for (int i = 1; i < 33; i++) lu = fmaf(x[i], x[i], lu);
    float f = dist * rsqrtf(fmaxf(lu, 1e-8f));
#pragma unroll
    for (int ch = 0; ch < 33; ch++) x[ch] *= f;
    float corr = -x[0] / (1.f + mu[0]);
    x[0] += corr * (mu[0] + 1.f);
#pragma unroll
    for (int i = 1; i < 33; i++) x[i] = fmaf(corr, mu[i], x[i]);
    float scb = bs[w] * rsqrtf(var + 1e-5f);
#pragma unroll
    for (int ch = 0; ch < 33; ch++) x[ch] *= scb;
    float nn = -x[0] * x[0];
#pragma unroll
    for (int i = 1; i < 33; i++) nn = fmaf(x[i], x[i], nn);
    float n = sqrtf(fmaxf(nn, 1e-9f));
    float shn = sinhf(n) / n;
    float sg = 0.f;
#pragma unroll
    for (int i = 1; i < 33; i++) {
        float e = shn * x[i];
        e = (e > 0.f) ? e : expm1f(e);
        x[i] = e;
        sg = fmaf(e, e, sg);
    }
    x[0] = sqrtf(1.f + sg);
    for (int jj = 0; jj < 4; jj++) {
        if (j == jj) {
#pragma unroll
            for (int ch = 0; ch < 33; ch++) lavg[b][ch] += x[ch];
        }
        __syncthreads();
    }
    if (tid < 128) {
        int bb2 = tid;
        float avg[33];
#pragma unroll
        for (int ch = 0; ch < 33; ch++) avg[ch] = lavg[bb2][ch] * 0.25f;
        float sp2 = 0.f;
#pragma unroll
        for (int i = 1; i < 33; i++) sp2 = fmaf(avg[i], avg[i], sp2);
        float l = avg[0] * avg[0] - sp2;
        float rd2 = rsqrtf(fmaxf(l, 1e-8f));
        float q0 = avg[0] * rd2;
        float* fb = outp + 512 + (size_t)bb2 * 4097;
#pragma unroll
        for (int i = 1; i < 33; i++) fb[1 + wp * 32 + (i - 1)] = avg[i] * rd2;
        qsq[bb2 * 128 + wp] = q0 * q0;
    }
}

// ---- merged: tnew + mlr prep + mlr logits ----
__global__ __launch_bounds__(256) void k_mlr2(
        const float* __restrict__ qsq, const float* __restrict__ z,
        const float* __restrict__ a, float* __restrict__ outp) {
    int b = blockIdx.x, tid = threadIdx.x;
    __shared__ float red[4][8];
    __shared__ float tnsh;
    if (tid < 64) {
        float s = qsq[b * 128 + tid] + qsq[b * 128 + 64 + tid];
#pragma unroll
        for (int d = 1; d < 64; d <<= 1) s += __shfl_xor(s, d);
        if (tid == 0) tnsh = sqrtf(fmaxf(s - 127.f, 1e-8f));
    }
    __syncthreads();
    float tn = tnsh;
    const float* fs = outp + 512 + (size_t)b * 4097 + 1;
    float sdot[4] = {0.f, 0.f, 0.f, 0.f}, sq[4] = {0.f, 0.f, 0.f, 0.f};
    for (int i = tid * 4; i < FEAT; i += 1024) {
        float f0 = fs[i], f1 = fs[i + 1], f2 = fs[i + 2], f3 = fs[i + 3];
#pragma unroll
        for (int c = 0; c < 4; c++) {
            float4 zv = *(const float4*)(z + c * FEAT + i);
            sdot[c] = fmaf(f0, zv.x, sdot[c]); sdot[c] = fmaf(f1, zv.y, sdot[c]);
            sdot[c] = fmaf(f2, zv.z, sdot[c]); sdot[c] = fmaf(f3, zv.w, sdot[c]);
            sq[c] = fmaf(zv.x, zv.x, sq[c]); sq[c] = fmaf(zv.y, zv.y, sq[c]);
            sq[c] = fmaf(zv.z, zv.z, sq[c]); sq[c] = fmaf(zv.w, zv.w, sq[c]);
        }
    }
#pragma unroll
    for (int d = 1; d < 64; d <<= 1) {
#pragma unroll
        for (int c = 0; c < 4; c++) {
            sdot[c] += __shfl_xor(sdot[c], d);
            sq[c]   += __shfl_xor(sq[c], d);
        }
    }
    int wv = tid >> 6;
    if ((tid & 63) == 0) {
#pragma unroll
        for (int c = 0; c < 4; c++) { red[wv][c] = sdot[c]; red[wv][4 + c] = sq[c]; }
    }
    __syncthreads();
    if (tid == 0) {
        outp[512 + (size_t)b * 4097] = tn;
#pragma unroll
        for (int c = 0; c < 4; c++) {
            float dot = red[0][c] + red[1][c] + red[2][c] + red[3][c];
            float qz  = red[0][4 + c] + red[1][4 + c] + red[2][4 + c] + red[3][4 + c];
            float nz = sqrtf(qz);
            float ca = coshf(a[c]), sa = sinhf(a[c]);
            float wt = sa * nz;
            float cb = ca * nz;
            float bb = sqrtf(fmaxf(cb * cb - wt * wt, 1e-8f));
            float alpha = fmaf(-tn, wt, ca * dot);
            float d = fabsf(asinhf(alpha / bb));
            float sg = (alpha > 0.f) ? 1.f : ((alpha < 0.f) ? -1.f : 0.f);
            outp[b * 4 + c] = sg * bb * d;
        }
    }
}

extern "C" void kernel_launch(void* const* d_in, const int* in_sizes, int n_in,
                              void* d_out, int out_size, void* d_ws, size_t ws_size,
                              hipStream_t stream) {
    const float* in   = (const float*)d_in[0];
    const float* w1   = (const float*)d_in[2];
    const float* g1   = (const float*)d_in[3];
    const float* w2   = (const float*)d_in[5];
    const float* g2   = (const float*)d_in[6];
    const float* b2   = (const float*)d_in[7];
    const float* ew   = (const float*)d_in[8];
    const float* lc1  = (const float*)d_in[9];
    const float* bs   = (const float*)d_in[10];
    const float* mlra = (const float*)d_in[11];
    const float* mlrz = (const float*)d_in[12];
    float* out = (float*)d_out;
    float* ws = (float*)d_ws;

    unsigned short* P  = (unsigned short*)(ws + OFF_P);
    unsigned short* X2 = (unsigned short*)(ws + OFF_X2);
    float* PSUM = ws + OFF_PSUM;
    float* PSQ  = ws + OFF_PSQ;
    float* SS   = ws + OFF_SS;
    unsigned short* Y = (unsigned short*)(ws + OFF_Y);
    float* ZZ   = ws + OFF_ZZ;
    float* QSQ  = ws + OFF_QSQ;

    k_p<<<dim3(8, 128), 256, 0, stream>>>(in, w2, P);
    k_cs<<<dim3(8, 128), 256, 0, stream>>>(P, w1, g1, X2, PSUM, PSQ);
    k_bn2fin<<<32, 64, 0, stream>>>(PSUM, PSQ, g2, b2, SS);
    k_pool2<<<8192, 256, 0, stream>>>(X2, SS, Y);
    k_ec1<<<dim3(8, 128), 256, 0, stream>>>(Y, ew, ZZ);
    k_tail<<<128, 512, 0, stream>>>(ZZ, lc1, bs, out, QSQ);
    k_mlr2<<<128, 256, 0, stream>>>(QSQ, mlrz, mlra, out);
}

// Round 6
// 208.858 us; speedup vs baseline: 1.6312x; 1.0108x over previous
//
#include <hip/hip_runtime.h>
#include <math.h>

#define BB 128
#define EE 64
#define TT 2048
#define C2 32
#define W1 2049
#define WPW 512
#define FEAT 4096
#define NBLK 1024

// float offsets in ws
#define OFF_P    ((size_t)0)          // bf16 P: 128*32*2048 ushort = 4,194,304 float slots
#define OFF_X2   ((size_t)4194304)    // bf16 X2: 4,194,304
#define OFF_PSUM ((size_t)8388608)    // 32*1024
#define OFF_PSQ  ((size_t)8421376)    // 32*1024
#define OFF_SS   ((size_t)8454144)    // 64
#define OFF_ZZ   ((size_t)8454208)    // fp32 [512][128][32] = 2,097,152
#define OFF_QSQ  ((size_t)10551360)   // 128*128

__device__ __forceinline__ unsigned short f2b(float f) {
    unsigned int u = __float_as_uint(f);
    u += 0x7FFFu + ((u >> 16) & 1u);
    return (unsigned short)(u >> 16);
}
__device__ __forceinline__ float b2f(unsigned short s) {
    return __uint_as_float(((unsigned int)s) << 16);
}

// ---- P[b,c,t] = sum_e w2[c,e]*in[b,e,t], stored bf16 ----
__global__ __launch_bounds__(256) void k_p(const float* __restrict__ in,
        const float* __restrict__ w2, unsigned short* __restrict__ P) {
    int b = blockIdx.y, t0 = blockIdx.x * 256, tid = threadIdx.x;
    __shared__ unsigned short li[64][256];   // 32 KB bf16 input tile
    __shared__ float lw2s[32][64];           // 8 KB
    const float* ib = in + (size_t)b * EE * TT + t0;
    for (int j = tid; j < 64 * 64; j += 256) {
        int e = j >> 6, q = j & 63;
        float4 v = *(const float4*)(ib + e * TT + q * 4);
        li[e][q * 4 + 0] = f2b(v.x); li[e][q * 4 + 1] = f2b(v.y);
        li[e][q * 4 + 2] = f2b(v.z); li[e][q * 4 + 3] = f2b(v.w);
    }
    for (int j = tid; j < 2048; j += 256) lw2s[j >> 6][j & 63] = w2[j];
    __syncthreads();
    int cg = tid >> 6, colg = tid & 63;
    int c8 = cg * 8;
    float acc[4][8];
#pragma unroll
    for (int x = 0; x < 4; x++)
#pragma unroll
        for (int jj = 0; jj < 8; jj++) acc[x][jj] = 0.f;
    for (int e = 0; e < 64; e += 2) {
        uint2 r0 = *(const uint2*)&li[e][colg * 4];
        uint2 r1 = *(const uint2*)&li[e + 1][colg * 4];
        float v0[4], v1[4];
        v0[0] = __uint_as_float(r0.x << 16); v0[1] = __uint_as_float(r0.x & 0xFFFF0000u);
        v0[2] = __uint_as_float(r0.y << 16); v0[3] = __uint_as_float(r0.y & 0xFFFF0000u);
        v1[0] = __uint_as_float(r1.x << 16); v1[1] = __uint_as_float(r1.x & 0xFFFF0000u);
        v1[2] = __uint_as_float(r1.y << 16); v1[3] = __uint_as_float(r1.y & 0xFFFF0000u);
#pragma unroll
        for (int jj = 0; jj < 8; jj++) {
            float2 wv = *(const float2*)&lw2s[c8 + jj][e];
#pragma unroll
            for (int x = 0; x < 4; x++) {
                acc[x][jj] = fmaf(wv.x, v0[x], acc[x][jj]);
                acc[x][jj] = fmaf(wv.y, v1[x], acc[x][jj]);
            }
        }
    }
    unsigned short* Pb = P + (size_t)b * C2 * TT + t0 + colg * 4;
#pragma unroll
    for (int jj = 0; jj < 8; jj++) {
        int c = c8 + jj;
        uint2 o;
        o.x = (unsigned int)f2b(acc[0][jj]) | ((unsigned int)f2b(acc[1][jj]) << 16);
        o.y = (unsigned int)f2b(acc[2][jj]) | ((unsigned int)f2b(acc[3][jj]) << 16);
        *(uint2*)(Pb + (size_t)c * TT) = o;
    }
}

// ---- conv1(32 taps) + sign(bn1_gamma) + X2(bf16) + bn2 partial stats ----
__global__ __launch_bounds__(256) void k_cs(const unsigned short* __restrict__ P,
        const float* __restrict__ w1, const float* __restrict__ g1,
        unsigned short* __restrict__ x2, float* __restrict__ psum, float* __restrict__ psq) {
    int bx = blockIdx.x, b = blockIdx.y, w0 = bx * 256, tid = threadIdx.x;
    __shared__ unsigned short lp[32][288];   // 18 KB
    __shared__ float lw1[16][32];
    __shared__ float lds_s[32], lds_q[32];
    const unsigned short* Pb = P + (size_t)b * C2 * TT;
    for (int j = tid; j < 32 * 72; j += 256) {
        int c = j / 72, g4 = j % 72;
        int t = w0 - 16 + g4 * 4;
        uint2 v = make_uint2(0u, 0u);
        if (t >= 0 && t + 3 < TT) v = *(const uint2*)(Pb + (size_t)c * TT + t);
        *(uint2*)&lp[c][g4 * 4] = v;
    }
    for (int j = tid; j < 512; j += 256) {
        int g = j >> 5;
        float sgn = (g1[g] < 0.f) ? -1.f : 1.f;
        lw1[g][j & 31] = w1[j] * sgn;
    }
    __syncthreads();
    for (int r = 0; r < 8; r++) {
        int task = r * 256 + tid;
        int c = task >> 6;          // wave-uniform
        int wq = task & 63;
        int wbase = wq * 4;
        float win[36];
#pragma unroll
        for (int i = 0; i < 9; i++) {
            uint2 v = *(const uint2*)&lp[c][wbase + i * 4];
            win[i * 4 + 0] = __uint_as_float(v.x << 16);
            win[i * 4 + 1] = __uint_as_float(v.x & 0xFFFF0000u);
            win[i * 4 + 2] = __uint_as_float(v.y << 16);
            win[i * 4 + 3] = __uint_as_float(v.y & 0xFFFF0000u);
        }
        const float* wc = lw1[c >> 1];
        float ls = 0.f, lq = 0.f;
        float accs[4];
#pragma unroll
        for (int i = 0; i < 4; i++) {
            float acc = 0.f;
#pragma unroll
            for (int k = 0; k < 32; k++) acc = fmaf(wc[k], win[i + k], acc);
            accs[i] = acc;
            ls += acc; lq = fmaf(acc, acc, lq);
        }
        uint2 o;
        o.x = (unsigned int)f2b(accs[0]) | ((unsigned int)f2b(accs[1]) << 16);
        o.y = (unsigned int)f2b(accs[2]) | ((unsigned int)f2b(accs[3]) << 16);
        *(uint2*)(x2 + ((size_t)b * C2 + c) * TT + w0 + wbase) = o;
#pragma unroll
        for (int d = 1; d < 64; d <<= 1) {
            ls += __shfl_xor(ls, d);
            lq += __shfl_xor(lq, d);
        }
        if ((tid & 63) == 0) { lds_s[c] = ls; lds_q[c] = lq; }
    }
    __syncthreads();
    if (bx == 7 && tid < 32) {      // stats for w=2048 (taps beyond t=2047 are zero-padded)
        const float* wc = lw1[tid >> 1];
        float acc = 0.f;
#pragma unroll
        for (int k = 0; k < 16; k++) acc = fmaf(wc[k], b2f(lp[tid][256 + k]), acc);
        lds_s[tid] += acc;
        lds_q[tid] += acc * acc;
    }
    __syncthreads();
    if (tid < 32) {
        int blk = b * 8 + bx;
        psum[tid * NBLK + blk] = lds_s[tid];
        psq[tid * NBLK + blk]  = lds_q[tid];
    }
}

__global__ __launch_bounds__(64) void k_bn2fin(
        const float* __restrict__ psum, const float* __restrict__ psq,
        const float* __restrict__ gamma, const float* __restrict__ beta,
        float* __restrict__ ss) {
    int c = blockIdx.x, l = threadIdx.x;
    float s = 0.f, q = 0.f;
    for (int j = l; j < NBLK; j += 64) { s += psum[c * NBLK + j]; q += psq[c * NBLK + j]; }
#pragma unroll
    for (int d = 1; d < 64; d <<= 1) { s += __shfl_xor(s, d); q += __shfl_xor(q, d); }
    if (l == 0) {
        float n = (float)(BB * W1);
        float m = s / n;
        float var = q / n - m * m;
        float sc = gamma[c] * rsqrtf(var + 1e-3f);
        ss[c] = sc;
        ss[32 + c] = beta[c] - m * sc;
    }
}

// ---- fused: bn2 + elu + avgpool4 + ec1 depthwise conv -> zz[w][b][c] ----
__global__ __launch_bounds__(256) void k_mid(
        const unsigned short* __restrict__ x2, const float* __restrict__ ss,
        const float* __restrict__ ew, float* __restrict__ zz) {
    int b = blockIdx.y, w0 = blockIdx.x * 64, tid = threadIdx.x;
    __shared__ unsigned short lx[32][324];   // x2 cols t = 4w0-32 .. 4w0+287 (320 used)
    __shared__ float ly[32][82];             // y cols w0-8 .. w0+71 (80 used)
    __shared__ float lss[64];
    __shared__ float lew[32][17];
    const unsigned short* xb = x2 + (size_t)b * C2 * TT;
    int base_t = 4 * w0 - 32;
    for (int it = 0; it < 10; it++) {
        int idx = it * 256 + tid;
        int c = idx / 80, q = idx - c * 80;
        int t0 = base_t + q * 4;
        uint2 v = make_uint2(0u, 0u);
        if (t0 >= 0 && t0 <= TT - 4) v = *(const uint2*)(xb + (size_t)c * TT + t0);
        *(uint2*)&lx[c][q * 4] = v;
    }
    if (tid < 64) lss[tid] = ss[tid];
    for (int j = tid; j < 512; j += 256) lew[j >> 4][j & 15] = ew[j];
    __syncthreads();
    // pool: ly[c][j2] = y[c][w0-8+j2]
    for (int it = 0; it < 10; it++) {
        int idx = it * 256 + tid;
        int c = idx & 31, j2 = idx >> 5;
        int ty = w0 - 8 + j2;
        float r = 0.f;
        if (ty >= 0 && ty < WPW) {
            uint2 v = *(const uint2*)&lx[c][j2 * 4];
            float sc = lss[c], sh = lss[32 + c];
            float a0 = fmaf(sc, __uint_as_float(v.x << 16), sh);
            float a1 = fmaf(sc, __uint_as_float(v.x & 0xFFFF0000u), sh);
            float a2 = fmaf(sc, __uint_as_float(v.y << 16), sh);
            float a3 = fmaf(sc, __uint_as_float(v.y & 0xFFFF0000u), sh);
            r = ((a0 > 0.f) ? a0 : expm1f(a0)) + ((a1 > 0.f) ? a1 : expm1f(a1))
              + ((a2 > 0.f) ? a2 : expm1f(a2)) + ((a3 > 0.f) ? a3 : expm1f(a3));
            r *= 0.25f;
        }
        ly[c][j2] = r;
    }
    __syncthreads();
    // ec1: 16-tap depthwise conv, 8 outputs per thread
    int c = tid & 31, wl = tid >> 5;
    float win[24];
#pragma unroll
    for (int m = 0; m < 12; m++) {
        float2 v = *(const float2*)&ly[c][wl * 8 + m * 2];
        win[m * 2] = v.x; win[m * 2 + 1] = v.y;
    }
    float wc[16];
#pragma unroll
    for (int k = 0; k < 16; k++) wc[k] = lew[c][k];
    float* zb = zz + ((size_t)(w0 + wl * 8) * BB + b) * C2 + c;
#pragma unroll
    for (int i = 0; i < 8; i++) {
        float acc = 0.f;
#pragma unroll
        for (int k = 0; k < 16; k++) acc = fmaf(wc[k], win[i + k], acc);
        zb[(size_t)i * BB * C2] = acc;
    }
}

// ---- fused: normalize + lc1 matvec + lorentz_bn + elu + lorentz pool + flatten ----
__global__ __launch_bounds__(512) void k_tail(
        const float* __restrict__ zz, const float* __restrict__ lc1,
        const float* __restrict__ bs, float* __restrict__ outp,
        float* __restrict__ qsq) {
    int wp = blockIdx.x;            // 0..127
    int tid = threadIdx.x;          // 512
    int j = tid >> 7;               // w offset 0..3
    int b = tid & 127;
    int w = wp * 4 + j;
    __shared__ float lws[33][32];   // spatial weights, 16B-aligned rows
    __shared__ float lwt[33];       // time-column weights
    __shared__ float wsum[4][2][33];
    __shared__ float vred[4][2];
    __shared__ float lavg[128][33];
    for (int i = tid; i < 1089; i += 512) {
        int o = i / 33, ii = i - o * 33;
        float v = lc1[i];
        if (ii == 0) lwt[o] = v; else lws[o][ii - 1] = v;
    }
    float* lz = &lavg[0][0];
    for (int i = tid; i < 128 * 33; i += 512) lz[i] = 0.f;
    __syncthreads();
    float x[33];
    {
        float xin[32];
        float ssq = 0.f;
        const float* zp = zz + ((size_t)w * BB + b) * C2;
#pragma unroll
        for (int i = 0; i < 32; i += 4) {
            float4 v = *(const float4*)(zp + i);
            xin[i] = v.x; xin[i + 1] = v.y; xin[i + 2] = v.z; xin[i + 3] = v.w;
        }
#pragma unroll
        for (int i = 0; i < 32; i++) ssq = fmaf(xin[i], xin[i], ssq);
        float inv = 1.f / (sqrtf(ssq) + 1e-8f);
        float s2 = 0.f;
#pragma unroll
        for (int i = 0; i < 32; i++) { xin[i] *= inv; s2 = fmaf(xin[i], xin[i], s2); }
        float t = sqrtf(1.f + s2);
        float pre0 = fmaxf(t, 1.f);
        float sy = 0.f;
        for (int o = 1; o < 33; o++) {
            float a = lwt[o] * pre0;
#pragma unroll
            for (int q4 = 0; q4 < 8; q4++) {
                float4 wv = *(const float4*)&lws[o][q4 * 4];
                a = fmaf(wv.x, xin[q4 * 4 + 0], a);
                a = fmaf(wv.y, xin[q4 * 4 + 1], a);
                a = fmaf(wv.z, xin[q4 * 4 + 2], a);
                a = fmaf(wv.w, xin[q4 * 4 + 3], a);
            }
            x[o] = a;
            sy = fmaf(a, a, sy);
        }
        x[0] = sqrtf(1.f + sy);
    }
    float mu[33];
#pragma unroll
    for (int ch = 0; ch < 33; ch++) {
        float s = x[ch];
        s += __shfl_xor(s, 1);  s += __shfl_xor(s, 2);  s += __shfl_xor(s, 4);
        s += __shfl_xor(s, 8);  s += __shfl_xor(s, 16); s += __shfl_xor(s, 32);
        mu[ch] = s;
    }
    int wv = b >> 6;
    if ((b & 63) == 0) {
#pragma unroll
        for (int ch = 0; ch < 33; ch++) wsum[j][wv][ch] = mu[ch];
    }
    __syncthreads();
#pragma unroll
    for (int ch = 0; ch < 33; ch++) mu[ch] = (wsum[j][0][ch] + wsum[j][1][ch]) * (1.f / 128.f);
    float a0 = mu[0], sp = 0.f;
#pragma unroll
    for (int i = 1; i < 33; i++) sp = fmaf(mu[i], mu[i], sp);
    float rd = rsqrtf(fmaxf(a0 * a0 - sp, 1e-8f));
#pragma unroll
    for (int ch = 0; ch < 33; ch++) mu[ch] *= rd;
    float xin2 = x[0] * mu[0];
#pragma unroll
    for (int i = 1; i < 33; i++) xin2 -= x[i] * mu[i];
    float dist = acoshf(fmaxf(xin2, 1.f + 1e-7f));
    float dq = dist * dist;
    dq += __shfl_xor(dq, 1);  dq += __shfl_xor(dq, 2);  dq += __shfl_xor(dq, 4);
    dq += __shfl_xor(dq, 8);  dq += __shfl_xor(dq, 16); dq += __shfl_xor(dq, 32);
    if ((b & 63) == 0) vred[j][wv] = dq;
    __syncthreads();
    float var = (vred[j][0] + vred[j][1]) * (1.f / 128.f);
#pragma unroll
    for (int ch = 0; ch < 33; ch++) x[ch] = x[ch] - xin2 * mu[ch];
    float lu = -x[0] * x[0];
#pragma unroll
    for (int i = 1; i < 33; i++) lu = fmaf(x[i], x[i], lu);
    float f = dist * rsqrtf(fmaxf(lu, 1e-8f));
#pragma unroll
    for (int ch = 0; ch < 33; ch++) x[ch] *= f;
    float corr = -x[0] / (1.f + mu[0]);
    x[0] += corr * (mu[0] + 1.f);
#pragma unroll
    for (int i = 1; i < 33; i++) x[i] = fmaf(corr, mu[i], x[i]);
    float scb = bs[w] * rsqrtf(var + 1e-5f);
#pragma unroll
    for (int ch = 0; ch < 33; ch++) x[ch] *= scb;
    float nn = -x[0] * x[0];
#pragma unroll
    for (int i = 1; i < 33; i++) nn = fmaf(x[i], x[i], nn);
    float n = sqrtf(fmaxf(nn, 1e-9f));
    float shn = sinhf(n) / n;
    float sg = 0.f;
#pragma unroll
    for (int i = 1; i < 33; i++) {
        float e = shn * x[i];
        e = (e > 0.f) ? e : expm1f(e);
        x[i] = e;
        sg = fmaf(e, e, sg);
    }
    x[0] = sqrtf(1.f + sg);
    for (int jj = 0; jj < 4; jj++) {
        if (j == jj) {
#pragma unroll
            for (int ch = 0; ch < 33; ch++) lavg[b][ch] += x[ch];
        }
        __syncthreads();
    }
    if (tid < 128) {
        int bb2 = tid;
        float avg[33];
#pragma unroll
        for (int ch = 0; ch < 33; ch++) avg[ch] = lavg[bb2][ch] * 0.25f;
        float sp2 = 0.f;
#pragma unroll
        for (int i = 1; i < 33; i++) sp2 = fmaf(avg[i], avg[i], sp2);
        float l = avg[0] * avg[0] - sp2;
        float rd2 = rsqrtf(fmaxf(l, 1e-8f));
        float q0 = avg[0] * rd2;
        float* fb = outp + 512 + (size_t)bb2 * 4097;
#pragma unroll
        for (int i = 1; i < 33; i++) fb[1 + wp * 32 + (i - 1)] = avg[i] * rd2;
        qsq[bb2 * 128 + wp] = q0 * q0;
    }
}

// ---- merged: tnew + mlr prep + mlr logits ----
__global__ __launch_bounds__(256) void k_mlr2(
        const float* __restrict__ qsq, const float* __restrict__ z,
        const float* __restrict__ a, float* __restrict__ outp) {
    int b = blockIdx.x, tid = threadIdx.x;
    __shared__ float red[4][8];
    __shared__ float tnsh;
    if (tid < 64) {
        float s = qsq[b * 128 + tid] + qsq[b * 128 + 64 + tid];
#pragma unroll
        for (int d = 1; d < 64; d <<= 1) s += __shfl_xor(s, d);
        if (tid == 0) tnsh = sqrtf(fmaxf(s - 127.f, 1e-8f));
    }
    __syncthreads();
    float tn = tnsh;
    const float* fs = outp + 512 + (size_t)b * 4097 + 1;
    float sdot[4] = {0.f, 0.f, 0.f, 0.f}, sq[4] = {0.f, 0.f, 0.f, 0.f};
    for (int i = tid * 4; i < FEAT; i += 1024) {
        float f0 = fs[i], f1 = fs[i + 1], f2 = fs[i + 2], f3 = fs[i + 3];
#pragma unroll
        for (int c = 0; c < 4; c++) {
            float4 zv = *(const float4*)(z + c * FEAT + i);
            sdot[c] = fmaf(f0, zv.x, sdot[c]); sdot[c] = fmaf(f1, zv.y, sdot[c]);
            sdot[c] = fmaf(f2, zv.z, sdot[c]); sdot[c] = fmaf(f3, zv.w, sdot[c]);
            sq[c] = fmaf(zv.x, zv.x, sq[c]); sq[c] = fmaf(zv.y, zv.y, sq[c]);
            sq[c] = fmaf(zv.z, zv.z, sq[c]); sq[c] = fmaf(zv.w, zv.w, sq[c]);
        }
    }
#pragma unroll
    for (int d = 1; d < 64; d <<= 1) {
#pragma unroll
        for (int c = 0; c < 4; c++) {
            sdot[c] += __shfl_xor(sdot[c], d);
            sq[c]   += __shfl_xor(sq[c], d);
        }
    }
    int wv = tid >> 6;
    if ((tid & 63) == 0) {
#pragma unroll
        for (int c = 0; c < 4; c++) { red[wv][c] = sdot[c]; red[wv][4 + c] = sq[c]; }
    }
    __syncthreads();
    if (tid == 0) {
        outp[512 + (size_t)b * 4097] = tn;
#pragma unroll
        for (int c = 0; c < 4; c++) {
            float dot = red[0][c] + red[1][c] + red[2][c] + red[3][c];
            float qz  = red[0][4 + c] + red[1][4 + c] + red[2][4 + c] + red[3][4 + c];
            float nz = sqrtf(qz);
            float ca = coshf(a[c]), sa = sinhf(a[c]);
            float wt = sa * nz;
            float cb = ca * nz;
            float bb = sqrtf(fmaxf(cb * cb - wt * wt, 1e-8f));
            float alpha = fmaf(-tn, wt, ca * dot);
            float d = fabsf(asinhf(alpha / bb));
            float sg = (alpha > 0.f) ? 1.f : ((alpha < 0.f) ? -1.f : 0.f);
            outp[b * 4 + c] = sg * bb * d;
        }
    }
}

extern "C" void kernel_launch(void* const* d_in, const int* in_sizes, int n_in,
                              void* d_out, int out_size, void* d_ws, size_t ws_size,
                              hipStream_t stream) {
    const float* in   = (const float*)d_in[0];
    const float* w1   = (const float*)d_in[2];
    const float* g1   = (const float*)d_in[3];
    const float* w2   = (const float*)d_in[5];
    const float* g2   = (const float*)d_in[6];
    const float* b2   = (const float*)d_in[7];
    const float* ew   = (const float*)d_in[8];
    const float* lc1  = (const float*)d_in[9];
    const float* bs   = (const float*)d_in[10];
    const float* mlra = (const float*)d_in[11];
    const float* mlrz = (const float*)d_in[12];
    float* out = (float*)d_out;
    float* ws = (float*)d_ws;

    unsigned short* P  = (unsigned short*)(ws + OFF_P);
    unsigned short* X2 = (unsigned short*)(ws + OFF_X2);
    float* PSUM = ws + OFF_PSUM;
    float* PSQ  = ws + OFF_PSQ;
    float* SS   = ws + OFF_SS;
    float* ZZ   = ws + OFF_ZZ;
    float* QSQ  = ws + OFF_QSQ;

    k_p<<<dim3(8, 128), 256, 0, stream>>>(in, w2, P);
    k_cs<<<dim3(8, 128), 256, 0, stream>>>(P, w1, g1, X2, PSUM, PSQ);
    k_bn2fin<<<32, 64, 0, stream>>>(PSUM, PSQ, g2, b2, SS);
    k_mid<<<dim3(8, 128), 256, 0, stream>>>(X2, SS, ew, ZZ);
    k_tail<<<128, 512, 0, stream>>>(ZZ, lc1, bs, out, QSQ);
    k_mlr2<<<128, 256, 0, stream>>>(QSQ, mlrz, mlra, out);
}

// Round 7
// 203.591 us; speedup vs baseline: 1.6734x; 1.0259x over previous
//
#include <hip/hip_runtime.h>
#include <math.h>

#define BB 128
#define EE 64
#define TT 2048
#define C2 32
#define W1 2049
#define WPW 512
#define FEAT 4096
#define NBLK 1024

// float offsets in ws
#define OFF_P    ((size_t)0)          // bf16 P: 128*32*2048 ushort = 4,194,304 float slots
#define OFF_X2   ((size_t)4194304)    // bf16 X2
#define OFF_PSUM ((size_t)8388608)    // 32*1024
#define OFF_PSQ  ((size_t)8421376)    // 32*1024
#define OFF_SS   ((size_t)8454144)    // 64
#define OFF_H    ((size_t)8454208)    // fp32 [512][128][33] = 2,162,688
#define OFF_QSQ  ((size_t)10616896)   // 128*128

__device__ __forceinline__ unsigned short f2b(float f) {
    unsigned int u = __float_as_uint(f);
    u += 0x7FFFu + ((u >> 16) & 1u);
    return (unsigned short)(u >> 16);
}
__device__ __forceinline__ float b2f(unsigned short s) {
    return __uint_as_float(((unsigned int)s) << 16);
}

// ---- P[b,c,t] = sum_e w2[c,e]*in[b,e,t], stored bf16 ----
__global__ __launch_bounds__(256) void k_p(const float* __restrict__ in,
        const float* __restrict__ w2, unsigned short* __restrict__ P) {
    int b = blockIdx.y, t0 = blockIdx.x * 256, tid = threadIdx.x;
    __shared__ unsigned short li[64][256];
    __shared__ float lw2s[32][64];
    const float* ib = in + (size_t)b * EE * TT + t0;
    for (int j = tid; j < 64 * 64; j += 256) {
        int e = j >> 6, q = j & 63;
        float4 v = *(const float4*)(ib + e * TT + q * 4);
        li[e][q * 4 + 0] = f2b(v.x); li[e][q * 4 + 1] = f2b(v.y);
        li[e][q * 4 + 2] = f2b(v.z); li[e][q * 4 + 3] = f2b(v.w);
    }
    for (int j = tid; j < 2048; j += 256) lw2s[j >> 6][j & 63] = w2[j];
    __syncthreads();
    int cg = tid >> 6, colg = tid & 63;
    int c8 = cg * 8;
    float acc[4][8];
#pragma unroll
    for (int x = 0; x < 4; x++)
#pragma unroll
        for (int jj = 0; jj < 8; jj++) acc[x][jj] = 0.f;
    for (int e = 0; e < 64; e += 2) {
        uint2 r0 = *(const uint2*)&li[e][colg * 4];
        uint2 r1 = *(const uint2*)&li[e + 1][colg * 4];
        float v0[4], v1[4];
        v0[0] = __uint_as_float(r0.x << 16); v0[1] = __uint_as_float(r0.x & 0xFFFF0000u);
        v0[2] = __uint_as_float(r0.y << 16); v0[3] = __uint_as_float(r0.y & 0xFFFF0000u);
        v1[0] = __uint_as_float(r1.x << 16); v1[1] = __uint_as_float(r1.x & 0xFFFF0000u);
        v1[2] = __uint_as_float(r1.y << 16); v1[3] = __uint_as_float(r1.y & 0xFFFF0000u);
#pragma unroll
        for (int jj = 0; jj < 8; jj++) {
            float2 wv = *(const float2*)&lw2s[c8 + jj][e];
#pragma unroll
            for (int x = 0; x < 4; x++) {
                acc[x][jj] = fmaf(wv.x, v0[x], acc[x][jj]);
                acc[x][jj] = fmaf(wv.y, v1[x], acc[x][jj]);
            }
        }
    }
    unsigned short* Pb = P + (size_t)b * C2 * TT + t0 + colg * 4;
#pragma unroll
    for (int jj = 0; jj < 8; jj++) {
        int c = c8 + jj;
        uint2 o;
        o.x = (unsigned int)f2b(acc[0][jj]) | ((unsigned int)f2b(acc[1][jj]) << 16);
        o.y = (unsigned int)f2b(acc[2][jj]) | ((unsigned int)f2b(acc[3][jj]) << 16);
        *(uint2*)(Pb + (size_t)c * TT) = o;
    }
}

// ---- conv1(32 taps) + sign(bn1_gamma) + X2(bf16) + bn2 partial stats ----
__global__ __launch_bounds__(256) void k_cs(const unsigned short* __restrict__ P,
        const float* __restrict__ w1, const float* __restrict__ g1,
        unsigned short* __restrict__ x2, float* __restrict__ psum, float* __restrict__ psq) {
    int bx = blockIdx.x, b = blockIdx.y, w0 = bx * 256, tid = threadIdx.x;
    __shared__ unsigned short lp[32][288];
    __shared__ float lw1[16][32];
    __shared__ float lds_s[32], lds_q[32];
    const unsigned short* Pb = P + (size_t)b * C2 * TT;
    for (int j = tid; j < 32 * 72; j += 256) {
        int c = j / 72, g4 = j % 72;
        int t = w0 - 16 + g4 * 4;
        uint2 v = make_uint2(0u, 0u);
        if (t >= 0 && t + 3 < TT) v = *(const uint2*)(Pb + (size_t)c * TT + t);
        *(uint2*)&lp[c][g4 * 4] = v;
    }
    for (int j = tid; j < 512; j += 256) {
        int g = j >> 5;
        float sgn = (g1[g] < 0.f) ? -1.f : 1.f;
        lw1[g][j & 31] = w1[j] * sgn;
    }
    __syncthreads();
    for (int r = 0; r < 8; r++) {
        int task = r * 256 + tid;
        int c = task >> 6;          // wave-uniform
        int wq = task & 63;
        int wbase = wq * 4;
        float win[36];
#pragma unroll
        for (int i = 0; i < 9; i++) {
            uint2 v = *(const uint2*)&lp[c][wbase + i * 4];
            win[i * 4 + 0] = __uint_as_float(v.x << 16);
            win[i * 4 + 1] = __uint_as_float(v.x & 0xFFFF0000u);
            win[i * 4 + 2] = __uint_as_float(v.y << 16);
            win[i * 4 + 3] = __uint_as_float(v.y & 0xFFFF0000u);
        }
        const float* wc = lw1[c >> 1];
        float ls = 0.f, lq = 0.f;
        float accs[4];
#pragma unroll
        for (int i = 0; i < 4; i++) {
            float acc = 0.f;
#pragma unroll
            for (int k = 0; k < 32; k++) acc = fmaf(wc[k], win[i + k], acc);
            accs[i] = acc;
            ls += acc; lq = fmaf(acc, acc, lq);
        }
        uint2 o;
        o.x = (unsigned int)f2b(accs[0]) | ((unsigned int)f2b(accs[1]) << 16);
        o.y = (unsigned int)f2b(accs[2]) | ((unsigned int)f2b(accs[3]) << 16);
        *(uint2*)(x2 + ((size_t)b * C2 + c) * TT + w0 + wbase) = o;
#pragma unroll
        for (int d = 1; d < 64; d <<= 1) {
            ls += __shfl_xor(ls, d);
            lq += __shfl_xor(lq, d);
        }
        if ((tid & 63) == 0) { lds_s[c] = ls; lds_q[c] = lq; }
    }
    __syncthreads();
    if (bx == 7 && tid < 32) {      // stats for w=2048
        const float* wc = lw1[tid >> 1];
        float acc = 0.f;
#pragma unroll
        for (int k = 0; k < 16; k++) acc = fmaf(wc[k], b2f(lp[tid][256 + k]), acc);
        lds_s[tid] += acc;
        lds_q[tid] += acc * acc;
    }
    __syncthreads();
    if (tid < 32) {
        int blk = b * 8 + bx;
        psum[tid * NBLK + blk] = lds_s[tid];
        psq[tid * NBLK + blk]  = lds_q[tid];
    }
}

__global__ __launch_bounds__(64) void k_bn2fin(
        const float* __restrict__ psum, const float* __restrict__ psq,
        const float* __restrict__ gamma, const float* __restrict__ beta,
        float* __restrict__ ss) {
    int c = blockIdx.x, l = threadIdx.x;
    float s = 0.f, q = 0.f;
    for (int j = l; j < NBLK; j += 64) { s += psum[c * NBLK + j]; q += psq[c * NBLK + j]; }
#pragma unroll
    for (int d = 1; d < 64; d <<= 1) { s += __shfl_xor(s, d); q += __shfl_xor(q, d); }
    if (l == 0) {
        float n = (float)(BB * W1);
        float m = s / n;
        float var = q / n - m * m;
        float sc = gamma[c] * rsqrtf(var + 1e-3f);
        ss[c] = sc;
        ss[32 + c] = beta[c] - m * sc;
    }
}

// ---- fused: bn2+elu+pool4 + ec1 conv + L2norm + add_time + lc1 matvec + add_time
//      -> H[w][b][33].  Half-wave (32 lanes) holds one (w,b) row, channel per lane.
__global__ __launch_bounds__(256) void k_mid(
        const unsigned short* __restrict__ x2, const float* __restrict__ ss,
        const float* __restrict__ ew, const float* __restrict__ lc1,
        float* __restrict__ H) {
    int b = blockIdx.y, w0 = blockIdx.x * 64, tid = threadIdx.x;
    __shared__ unsigned short lx[32][324];
    __shared__ float ly[32][82];
    __shared__ float lss[64];
    __shared__ float lew[32][17];
    __shared__ float lc[1089];
    __shared__ float lxn[8][32];
    const unsigned short* xb = x2 + (size_t)b * C2 * TT;
    int base_t = 4 * w0 - 32;
    for (int it = 0; it < 10; it++) {
        int idx = it * 256 + tid;
        int c = idx / 80, q = idx - c * 80;
        int t0 = base_t + q * 4;
        uint2 v = make_uint2(0u, 0u);
        if (t0 >= 0 && t0 <= TT - 4) v = *(const uint2*)(xb + (size_t)c * TT + t0);
        *(uint2*)&lx[c][q * 4] = v;
    }
    if (tid < 64) lss[tid] = ss[tid];
    for (int j = tid; j < 512; j += 256) lew[j >> 4][j & 15] = ew[j];
    for (int j = tid; j < 1089; j += 256) lc[j] = lc1[j];
    __syncthreads();
    // pool: ly[c][j2] = y[c][w0-8+j2]
    for (int it = 0; it < 10; it++) {
        int idx = it * 256 + tid;
        int c = idx & 31, j2 = idx >> 5;
        int ty = w0 - 8 + j2;
        float r = 0.f;
        if (ty >= 0 && ty < WPW) {
            uint2 v = *(const uint2*)&lx[c][j2 * 4];
            float sc = lss[c], sh = lss[32 + c];
            float a0 = fmaf(sc, __uint_as_float(v.x << 16), sh);
            float a1 = fmaf(sc, __uint_as_float(v.x & 0xFFFF0000u), sh);
            float a2 = fmaf(sc, __uint_as_float(v.y << 16), sh);
            float a3 = fmaf(sc, __uint_as_float(v.y & 0xFFFF0000u), sh);
            r = ((a0 > 0.f) ? a0 : expm1f(a0)) + ((a1 > 0.f) ? a1 : expm1f(a1))
              + ((a2 > 0.f) ? a2 : expm1f(a2)) + ((a3 > 0.f) ? a3 : expm1f(a3));
            r *= 0.25f;
        }
        ly[c][j2] = r;
    }
    __syncthreads();
    // ec1: 16-tap depthwise conv, 8 outputs (w's) per thread
    int c = tid & 31, wl = tid >> 5;
    float win[24];
#pragma unroll
    for (int m = 0; m < 12; m++) {
        float2 v = *(const float2*)&ly[c][wl * 8 + m * 2];
        win[m * 2] = v.x; win[m * 2 + 1] = v.y;
    }
    float wc[16];
#pragma unroll
    for (int k = 0; k < 16; k++) wc[k] = lew[c][k];
    float acc[8];
#pragma unroll
    for (int i = 0; i < 8; i++) {
        float a = 0.f;
#pragma unroll
        for (int k = 0; k < 16; k++) a = fmaf(wc[k], win[i + k], a);
        acc[i] = a;
    }
    // head: per-lane output row o = c+1, weights in registers
    float wt0 = lc[(c + 1) * 33];
    float wreg[32];
#pragma unroll
    for (int k = 0; k < 32; k++) wreg[k] = lc[(c + 1) * 33 + 1 + k];
    float* lrow = lxn[wl];
#pragma unroll 1
    for (int i = 0; i < 8; i++) {
        float v = acc[i];
        float ssq = v * v;
        ssq += __shfl_xor(ssq, 1);  ssq += __shfl_xor(ssq, 2);
        ssq += __shfl_xor(ssq, 4);  ssq += __shfl_xor(ssq, 8);
        ssq += __shfl_xor(ssq, 16);
        float inv = 1.f / (sqrtf(ssq) + 1e-8f);
        float xn = v * inv;
        float s2 = ssq * inv * inv;
        float pre0 = fmaxf(sqrtf(1.f + s2), 1.f);
        lrow[c] = xn;               // warp-synchronous LDS broadcast row
        float y = wt0 * pre0;
#pragma unroll
        for (int q = 0; q < 8; q++) {
            float4 xv = *(const float4*)&lrow[q * 4];
            y = fmaf(wreg[q * 4 + 0], xv.x, y);
            y = fmaf(wreg[q * 4 + 1], xv.y, y);
            y = fmaf(wreg[q * 4 + 2], xv.z, y);
            y = fmaf(wreg[q * 4 + 3], xv.w, y);
        }
        float sy = y * y;
        sy += __shfl_xor(sy, 1);  sy += __shfl_xor(sy, 2);
        sy += __shfl_xor(sy, 4);  sy += __shfl_xor(sy, 8);
        sy += __shfl_xor(sy, 16);
        int w = w0 + wl * 8 + i;
        float* hrow = H + ((size_t)w * BB + b) * 33;
        hrow[1 + c] = y;
        if (c == 0) hrow[0] = sqrtf(1.f + sy);
    }
}

// ---- lorentz_bn + elu + lorentz pool + flatten (reads H) ----
__global__ __launch_bounds__(512) void k_tail(
        const float* __restrict__ H, const float* __restrict__ bs,
        float* __restrict__ outp, float* __restrict__ qsq) {
    int wp = blockIdx.x;            // 0..127
    int tid = threadIdx.x;          // 512
    int j = tid >> 7;               // w offset 0..3
    int b = tid & 127;
    int w = wp * 4 + j;
    __shared__ float wsum[4][2][33];
    __shared__ float vred[4][2];
    __shared__ float lavg[128][33];
    float* lz = &lavg[0][0];
    for (int i = tid; i < 128 * 33; i += 512) lz[i] = 0.f;
    float x[33];
    const float* hp = H + ((size_t)w * BB + b) * 33;
#pragma unroll
    for (int ch = 0; ch < 33; ch++) x[ch] = hp[ch];
    float mu[33];
#pragma unroll
    for (int ch = 0; ch < 33; ch++) {
        float s = x[ch];
        s += __shfl_xor(s, 1);  s += __shfl_xor(s, 2);  s += __shfl_xor(s, 4);
        s += __shfl_xor(s, 8);  s += __shfl_xor(s, 16); s += __shfl_xor(s, 32);
        mu[ch] = s;
    }
    int wv = b >> 6;
    if ((b & 63) == 0) {
#pragma unroll
        for (int ch = 0; ch < 33; ch++) wsum[j][wv][ch] = mu[ch];
    }
    __syncthreads();
#pragma unroll
    for (int ch = 0; ch < 33; ch++) mu[ch] = (wsum[j][0][ch] + wsum[j][1][ch]) * (1.f / 128.f);
    float a0 = mu[0], sp = 0.f;
#pragma unroll
    for (int i = 1; i < 33; i++) sp = fmaf(mu[i], mu[i], sp);
    float rd = rsqrtf(fmaxf(a0 * a0 - sp, 1e-8f));
#pragma unroll
    for (int ch = 0; ch < 33; ch++) mu[ch] *= rd;
    float xin2 = x[0] * mu[0];
#pragma unroll
    for (int i = 1; i < 33; i++) xin2 -= x[i] * mu[i];
    float dist = acoshf(fmaxf(xin2, 1.f + 1e-7f));
    float dq = dist * dist;
    dq += __shfl_xor(dq, 1);  dq += __shfl_xor(dq, 2);  dq += __shfl_xor(dq, 4);
    dq += __shfl_xor(dq, 8);  dq += __shfl_xor(dq, 16); dq += __shfl_xor(dq, 32);
    if ((b & 63) == 0) vred[j][wv] = dq;
    __syncthreads();
    float var = (vred[j][0] + vred[j][1]) * (1.f / 128.f);
#pragma unroll
    for (int ch = 0; ch < 33; ch++) x[ch] = x[ch] - xin2 * mu[ch];
    float lu = -x[0] * x[0];
#pragma unroll
    for (int i = 1; i < 33; i++) lu = fmaf(x[i], x[i], lu);
    float f = dist * rsqrtf(fmaxf(lu, 1e-8f));
#pragma unroll
    for (int ch = 0; ch < 33; ch++) x[ch] *= f;
    float corr = -x[0] / (1.f + mu[0]);
    x[0] += corr * (mu[0] + 1.f);
#pragma unroll
    for (int i = 1; i < 33; i++) x[i] = fmaf(corr, mu[i], x[i]);
    float scb = bs[w] * rsqrtf(var + 1e-5f);
#pragma unroll
    for (int ch = 0; ch < 33; ch++) x[ch] *= scb;
    float nn = -x[0] * x[0];
#pragma unroll
    for (int i = 1; i < 33; i++) nn = fmaf(x[i], x[i], nn);
    float n = sqrtf(fmaxf(nn, 1e-9f));
    float shn = sinhf(n) / n;
    float sg = 0.f;
#pragma unroll
    for (int i = 1; i < 33; i++) {
        float e = shn * x[i];
        e = (e > 0.f) ? e : expm1f(e);
        x[i] = e;
        sg = fmaf(e, e, sg);
    }
    x[0] = sqrtf(1.f + sg);
    for (int jj = 0; jj < 4; jj++) {
        if (j == jj) {
#pragma unroll
            for (int ch = 0; ch < 33; ch++) lavg[b][ch] += x[ch];
        }
        __syncthreads();
    }
    if (tid < 128) {
        int bb2 = tid;
        float avg[33];
#pragma unroll
        for (int ch = 0; ch < 33; ch++) avg[ch] = lavg[bb2][ch] * 0.25f;
        float sp2 = 0.f;
#pragma unroll
        for (int i = 1; i < 33; i++) sp2 = fmaf(avg[i], avg[i], sp2);
        float l = avg[0] * avg[0] - sp2;
        float rd2 = rsqrtf(fmaxf(l, 1e-8f));
        float q0 = avg[0] * rd2;
        float* fb = outp + 512 + (size_t)bb2 * 4097;
#pragma unroll
        for (int i = 1; i < 33; i++) fb[1 + wp * 32 + (i - 1)] = avg[i] * rd2;
        qsq[bb2 * 128 + wp] = q0 * q0;
    }
}

// ---- merged: tnew + mlr prep + mlr logits ----
__global__ __launch_bounds__(256) void k_mlr2(
        const float* __restrict__ qsq, const float* __restrict__ z,
        const float* __restrict__ a, float* __restrict__ outp) {
    int b = blockIdx.x, tid = threadIdx.x;
    __shared__ float red[4][8];
    __shared__ float tnsh;
    if (tid < 64) {
        float s = qsq[b * 128 + tid] + qsq[b * 128 + 64 + tid];
#pragma unroll
        for (int d = 1; d < 64; d <<= 1) s += __shfl_xor(s, d);
        if (tid == 0) tnsh = sqrtf(fmaxf(s - 127.f, 1e-8f));
    }
    __syncthreads();
    float tn = tnsh;
    const float* fs = outp + 512 + (size_t)b * 4097 + 1;
    float sdot[4] = {0.f, 0.f, 0.f, 0.f}, sq[4] = {0.f, 0.f, 0.f, 0.f};
    for (int i = tid * 4; i < FEAT; i += 1024) {
        float f0 = fs[i], f1 = fs[i + 1], f2 = fs[i + 2], f3 = fs[i + 3];
#pragma unroll
        for (int c = 0; c < 4; c++) {
            float4 zv = *(const float4*)(z + c * FEAT + i);
            sdot[c] = fmaf(f0, zv.x, sdot[c]); sdot[c] = fmaf(f1, zv.y, sdot[c]);
            sdot[c] = fmaf(f2, zv.z, sdot[c]); sdot[c] = fmaf(f3, zv.w, sdot[c]);
            sq[c] = fmaf(zv.x, zv.x, sq[c]); sq[c] = fmaf(zv.y, zv.y, sq[c]);
            sq[c] = fmaf(zv.z, zv.z, sq[c]); sq[c] = fmaf(zv.w, zv.w, sq[c]);
        }
    }
#pragma unroll
    for (int d = 1; d < 64; d <<= 1) {
#pragma unroll
        for (int c = 0; c < 4; c++) {
            sdot[c] += __shfl_xor(sdot[c], d);
            sq[c]   += __shfl_xor(sq[c], d);
        }
    }
    int wv = tid >> 6;
    if ((tid & 63) == 0) {
#pragma unroll
        for (int c = 0; c < 4; c++) { red[wv][c] = sdot[c]; red[wv][4 + c] = sq[c]; }
    }
    __syncthreads();
    if (tid == 0) {
        outp[512 + (size_t)b * 4097] = tn;
#pragma unroll
        for (int c = 0; c < 4; c++) {
            float dot = red[0][c] + red[1][c] + red[2][c] + red[3][c];
            float qz  = red[0][4 + c] + red[1][4 + c] + red[2][4 + c] + red[3][4 + c];
            float nz = sqrtf(qz);
            float ca = coshf(a[c]), sa = sinhf(a[c]);
            float wt = sa * nz;
            float cb = ca * nz;
            float bb = sqrtf(fmaxf(cb * cb - wt * wt, 1e-8f));
            float alpha = fmaf(-tn, wt, ca * dot);
            float d = fabsf(asinhf(alpha / bb));
            float sg = (alpha > 0.f) ? 1.f : ((alpha < 0.f) ? -1.f : 0.f);
            outp[b * 4 + c] = sg * bb * d;
        }
    }
}

extern "C" void kernel_launch(void* const* d_in, const int* in_sizes, int n_in,
                              void* d_out, int out_size, void* d_ws, size_t ws_size,
                              hipStream_t stream) {
    const float* in   = (const float*)d_in[0];
    const float* w1   = (const float*)d_in[2];
    const float* g1   = (const float*)d_in[3];
    const float* w2   = (const float*)d_in[5];
    const float* g2   = (const float*)d_in[6];
    const float* b2   = (const float*)d_in[7];
    const float* ew   = (const float*)d_in[8];
    const float* lc1  = (const float*)d_in[9];
    const float* bs   = (const float*)d_in[10];
    const float* mlra = (const float*)d_in[11];
    const float* mlrz = (const float*)d_in[12];
    float* out = (float*)d_out;
    float* ws = (float*)d_ws;

    unsigned short* P  = (unsigned short*)(ws + OFF_P);
    unsigned short* X2 = (unsigned short*)(ws + OFF_X2);
    float* PSUM = ws + OFF_PSUM;
    float* PSQ  = ws + OFF_PSQ;
    float* SS   = ws + OFF_SS;
    float* H    = ws + OFF_H;
    float* QSQ  = ws + OFF_QSQ;

    k_p<<<dim3(8, 128), 256, 0, stream>>>(in, w2, P);
    k_cs<<<dim3(8, 128), 256, 0, stream>>>(P, w1, g1, X2, PSUM, PSQ);
    k_bn2fin<<<32, 64, 0, stream>>>(PSUM, PSQ, g2, b2, SS);
    k_mid<<<dim3(8, 128), 256, 0, stream>>>(X2, SS, ew, lc1, H);
    k_tail<<<128, 512, 0, stream>>>(H, bs, out, QSQ);
    k_mlr2<<<128, 256, 0, stream>>>(QSQ, mlrz, mlra, out);
}

// Round 8
// 202.180 us; speedup vs baseline: 1.6850x; 1.0070x over previous
//
#include <hip/hip_runtime.h>
#include <math.h>

#define BB 128
#define EE 64
#define TT 2048
#define C2 32
#define W1 2049
#define WPW 512
#define FEAT 4096
#define NBLK 1024

// float offsets in ws
#define OFF_P    ((size_t)0)          // bf16 P: 128*32*2048 ushort
#define OFF_X2   ((size_t)4194304)    // bf16 X2
#define OFF_PSUM ((size_t)8388608)    // 32*1024
#define OFF_PSQ  ((size_t)8421376)    // 32*1024
#define OFF_SS   ((size_t)8454144)    // 64
#define OFF_H    ((size_t)8454208)    // fp32 [512][128][33] = 2,162,688
#define OFF_QSQ  ((size_t)10616896)   // 128*128
#define OFF_G    ((size_t)10633280)   // fp32 [512][128][33] = 2,162,688

__device__ __forceinline__ unsigned short f2b(float f) {
    unsigned int u = __float_as_uint(f);
    u += 0x7FFFu + ((u >> 16) & 1u);
    return (unsigned short)(u >> 16);
}
__device__ __forceinline__ float b2f(unsigned short s) {
    return __uint_as_float(((unsigned int)s) << 16);
}
__device__ __forceinline__ float elu_fast(float a) {
    return (a > 0.f) ? a : (__expf(a) - 1.f);
}

// ---- P[b,c,t] = sum_e w2[c,e]*in[b,e,t], stored bf16 ----
__global__ __launch_bounds__(256) void k_p(const float* __restrict__ in,
        const float* __restrict__ w2, unsigned short* __restrict__ P) {
    int b = blockIdx.y, t0 = blockIdx.x * 256, tid = threadIdx.x;
    __shared__ unsigned short li[64][256];
    __shared__ float lw2s[32][64];
    const float* ib = in + (size_t)b * EE * TT + t0;
    for (int j = tid; j < 64 * 64; j += 256) {
        int e = j >> 6, q = j & 63;
        float4 v = *(const float4*)(ib + e * TT + q * 4);
        li[e][q * 4 + 0] = f2b(v.x); li[e][q * 4 + 1] = f2b(v.y);
        li[e][q * 4 + 2] = f2b(v.z); li[e][q * 4 + 3] = f2b(v.w);
    }
    for (int j = tid; j < 2048; j += 256) lw2s[j >> 6][j & 63] = w2[j];
    __syncthreads();
    int cg = tid >> 6, colg = tid & 63;
    int c8 = cg * 8;
    float acc[4][8];
#pragma unroll
    for (int x = 0; x < 4; x++)
#pragma unroll
        for (int jj = 0; jj < 8; jj++) acc[x][jj] = 0.f;
    for (int e = 0; e < 64; e += 2) {
        uint2 r0 = *(const uint2*)&li[e][colg * 4];
        uint2 r1 = *(const uint2*)&li[e + 1][colg * 4];
        float v0[4], v1[4];
        v0[0] = __uint_as_float(r0.x << 16); v0[1] = __uint_as_float(r0.x & 0xFFFF0000u);
        v0[2] = __uint_as_float(r0.y << 16); v0[3] = __uint_as_float(r0.y & 0xFFFF0000u);
        v1[0] = __uint_as_float(r1.x << 16); v1[1] = __uint_as_float(r1.x & 0xFFFF0000u);
        v1[2] = __uint_as_float(r1.y << 16); v1[3] = __uint_as_float(r1.y & 0xFFFF0000u);
#pragma unroll
        for (int jj = 0; jj < 8; jj++) {
            float2 wv = *(const float2*)&lw2s[c8 + jj][e];
#pragma unroll
            for (int x = 0; x < 4; x++) {
                acc[x][jj] = fmaf(wv.x, v0[x], acc[x][jj]);
                acc[x][jj] = fmaf(wv.y, v1[x], acc[x][jj]);
            }
        }
    }
    unsigned short* Pb = P + (size_t)b * C2 * TT + t0 + colg * 4;
#pragma unroll
    for (int jj = 0; jj < 8; jj++) {
        int c = c8 + jj;
        uint2 o;
        o.x = (unsigned int)f2b(acc[0][jj]) | ((unsigned int)f2b(acc[1][jj]) << 16);
        o.y = (unsigned int)f2b(acc[2][jj]) | ((unsigned int)f2b(acc[3][jj]) << 16);
        *(uint2*)(Pb + (size_t)c * TT) = o;
    }
}

// ---- conv1(32 taps) + sign(bn1_gamma) + X2(bf16) + bn2 partial stats ----
__global__ __launch_bounds__(256) void k_cs(const unsigned short* __restrict__ P,
        const float* __restrict__ w1, const float* __restrict__ g1,
        unsigned short* __restrict__ x2, float* __restrict__ psum, float* __restrict__ psq) {
    int bx = blockIdx.x, b = blockIdx.y, w0 = bx * 256, tid = threadIdx.x;
    __shared__ unsigned short lp[32][288];
    __shared__ float lw1[16][32];
    __shared__ float lds_s[32], lds_q[32];
    const unsigned short* Pb = P + (size_t)b * C2 * TT;
    for (int j = tid; j < 32 * 72; j += 256) {
        int c = j / 72, g4 = j % 72;
        int t = w0 - 16 + g4 * 4;
        uint2 v = make_uint2(0u, 0u);
        if (t >= 0 && t + 3 < TT) v = *(const uint2*)(Pb + (size_t)c * TT + t);
        *(uint2*)&lp[c][g4 * 4] = v;
    }
    for (int j = tid; j < 512; j += 256) {
        int g = j >> 5;
        float sgn = (g1[g] < 0.f) ? -1.f : 1.f;
        lw1[g][j & 31] = w1[j] * sgn;
    }
    __syncthreads();
    for (int r = 0; r < 8; r++) {
        int task = r * 256 + tid;
        int c = task >> 6;          // wave-uniform
        int wq = task & 63;
        int wbase = wq * 4;
        float win[36];
#pragma unroll
        for (int i = 0; i < 9; i++) {
            uint2 v = *(const uint2*)&lp[c][wbase + i * 4];
            win[i * 4 + 0] = __uint_as_float(v.x << 16);
            win[i * 4 + 1] = __uint_as_float(v.x & 0xFFFF0000u);
            win[i * 4 + 2] = __uint_as_float(v.y << 16);
            win[i * 4 + 3] = __uint_as_float(v.y & 0xFFFF0000u);
        }
        const float* wc = lw1[c >> 1];
        float ls = 0.f, lq = 0.f;
        float accs[4];
#pragma unroll
        for (int i = 0; i < 4; i++) {
            float acc = 0.f;
#pragma unroll
            for (int k = 0; k < 32; k++) acc = fmaf(wc[k], win[i + k], acc);
            accs[i] = acc;
            ls += acc; lq = fmaf(acc, acc, lq);
        }
        uint2 o;
        o.x = (unsigned int)f2b(accs[0]) | ((unsigned int)f2b(accs[1]) << 16);
        o.y = (unsigned int)f2b(accs[2]) | ((unsigned int)f2b(accs[3]) << 16);
        *(uint2*)(x2 + ((size_t)b * C2 + c) * TT + w0 + wbase) = o;
#pragma unroll
        for (int d = 1; d < 64; d <<= 1) {
            ls += __shfl_xor(ls, d);
            lq += __shfl_xor(lq, d);
        }
        if ((tid & 63) == 0) { lds_s[c] = ls; lds_q[c] = lq; }
    }
    __syncthreads();
    if (bx == 7 && tid < 32) {      // stats for w=2048
        const float* wc = lw1[tid >> 1];
        float acc = 0.f;
#pragma unroll
        for (int k = 0; k < 16; k++) acc = fmaf(wc[k], b2f(lp[tid][256 + k]), acc);
        lds_s[tid] += acc;
        lds_q[tid] += acc * acc;
    }
    __syncthreads();
    if (tid < 32) {
        int blk = b * 8 + bx;
        psum[tid * NBLK + blk] = lds_s[tid];
        psq[tid * NBLK + blk]  = lds_q[tid];
    }
}

__global__ __launch_bounds__(64) void k_bn2fin(
        const float* __restrict__ psum, const float* __restrict__ psq,
        const float* __restrict__ gamma, const float* __restrict__ beta,
        float* __restrict__ ss) {
    int c = blockIdx.x, l = threadIdx.x;
    float s = 0.f, q = 0.f;
    for (int j = l; j < NBLK; j += 64) { s += psum[c * NBLK + j]; q += psq[c * NBLK + j]; }
#pragma unroll
    for (int d = 1; d < 64; d <<= 1) { s += __shfl_xor(s, d); q += __shfl_xor(q, d); }
    if (l == 0) {
        float n = (float)(BB * W1);
        float m = s / n;
        float var = q / n - m * m;
        float sc = gamma[c] * rsqrtf(var + 1e-3f);
        ss[c] = sc;
        ss[32 + c] = beta[c] - m * sc;
    }
}

// ---- fused: bn2+elu+pool4 + ec1 conv + L2norm + add_time + lc1 matvec + add_time
//      -> H[w][b][33].  Half-wave holds one (w,b) row, channel per lane. Batched ILP.
__global__ __launch_bounds__(256) void k_mid(
        const unsigned short* __restrict__ x2, const float* __restrict__ ss,
        const float* __restrict__ ew, const float* __restrict__ lc1,
        float* __restrict__ H) {
    int b = blockIdx.y, w0 = blockIdx.x * 64, tid = threadIdx.x;
    __shared__ __align__(16) float ly[32][82];
    __shared__ float lss[64];
    __shared__ float lew[32][17];
    __shared__ __align__(16) float lxn[8][8][32];
    if (tid < 64) lss[tid] = ss[tid];
    for (int j = tid; j < 512; j += 256) lew[j >> 4][j & 15] = ew[j];
    __syncthreads();
    // pool: ly[c][q] = y[c][w0-8+q], reading x2 directly from global (bf16 x4)
    const unsigned short* xb = x2 + (size_t)b * C2 * TT;
    for (int it = 0; it < 10; it++) {
        int idx = it * 256 + tid;
        int c = idx / 80, q = idx - c * 80;
        int ty = w0 - 8 + q;
        float r = 0.f;
        if (ty >= 0 && ty < WPW) {
            uint2 v = *(const uint2*)(xb + (size_t)c * TT + ty * 4);
            float sc = lss[c], sh = lss[32 + c];
            float a0 = elu_fast(fmaf(sc, __uint_as_float(v.x << 16), sh));
            float a1 = elu_fast(fmaf(sc, __uint_as_float(v.x & 0xFFFF0000u), sh));
            float a2 = elu_fast(fmaf(sc, __uint_as_float(v.y << 16), sh));
            float a3 = elu_fast(fmaf(sc, __uint_as_float(v.y & 0xFFFF0000u), sh));
            r = (a0 + a1 + a2 + a3) * 0.25f;
        }
        ly[c][q] = r;
    }
    __syncthreads();
    // ec1: 16-tap depthwise conv, 8 outputs (w's) per thread
    int c = tid & 31, wl = tid >> 5;
    float win[24];
#pragma unroll
    for (int m = 0; m < 12; m++) {
        float2 v = *(const float2*)&ly[c][wl * 8 + m * 2];
        win[m * 2] = v.x; win[m * 2 + 1] = v.y;
    }
    float wc[16];
#pragma unroll
    for (int k = 0; k < 16; k++) wc[k] = lew[c][k];
    float acc[8];
#pragma unroll
    for (int i = 0; i < 8; i++) {
        float a = 0.f;
#pragma unroll
        for (int k = 0; k < 16; k++) a = fmaf(wc[k], win[i + k], a);
        acc[i] = a;
    }
    // head phase A: batched norm reductions + broadcast rows to LDS
    float ss8[8];
#pragma unroll
    for (int i = 0; i < 8; i++) ss8[i] = acc[i] * acc[i];
#pragma unroll
    for (int d = 1; d < 32; d <<= 1) {
#pragma unroll
        for (int i = 0; i < 8; i++) ss8[i] += __shfl_xor(ss8[i], d);
    }
    float pre0[8];
#pragma unroll
    for (int i = 0; i < 8; i++) {
        float inv = 1.f / (sqrtf(ss8[i]) + 1e-8f);
        lxn[wl][i][c] = acc[i] * inv;       // wave-synchronous broadcast rows
        float s2 = ss8[i] * inv * inv;
        pre0[i] = fmaxf(sqrtf(1.f + s2), 1.f);
    }
    // head phase B: per-lane output row o=c+1, weights from L2 (broadcast)
    float wt0 = lc1[(c + 1) * 33];
    float wreg[32];
#pragma unroll
    for (int k = 0; k < 32; k++) wreg[k] = lc1[(c + 1) * 33 + 1 + k];
    float y8[8];
#pragma unroll
    for (int i = 0; i < 8; i++) {
        float y = wt0 * pre0[i];
#pragma unroll
        for (int q = 0; q < 8; q++) {
            float4 xv = *(const float4*)&lxn[wl][i][q * 4];
            y = fmaf(wreg[q * 4 + 0], xv.x, y);
            y = fmaf(wreg[q * 4 + 1], xv.y, y);
            y = fmaf(wreg[q * 4 + 2], xv.z, y);
            y = fmaf(wreg[q * 4 + 3], xv.w, y);
        }
        y8[i] = y;
    }
    float sy8[8];
#pragma unroll
    for (int i = 0; i < 8; i++) sy8[i] = y8[i] * y8[i];
#pragma unroll
    for (int d = 1; d < 32; d <<= 1) {
#pragma unroll
        for (int i = 0; i < 8; i++) sy8[i] += __shfl_xor(sy8[i], d);
    }
#pragma unroll
    for (int i = 0; i < 8; i++) {
        int w = w0 + wl * 8 + i;
        float* hrow = H + ((size_t)w * BB + b) * 33;
        hrow[1 + c] = y8[i];
        if (c == 0) hrow[0] = sqrtf(1.f + sy8[i]);
    }
}

// ---- lorentz_bn + elu: one w per block, 2 lanes per (w,b) row -> G[w][b][33] ----
__global__ __launch_bounds__(256) void k_tail2(
        const float* __restrict__ H, const float* __restrict__ bs,
        float* __restrict__ G) {
    int w = blockIdx.x;             // 0..511
    int tid = threadIdx.x;          // 256
    int l = tid & 1, b = tid >> 1;  // b 0..127, channels ch = 2k+l
    int wv = tid >> 6;              // wave 0..3 (32 rows each)
    __shared__ float wsum[4][2][17];
    __shared__ float vsum[4];
    float x[17];
    const float* hp = H + ((size_t)w * BB + b) * 33;
#pragma unroll
    for (int k = 0; k < 17; k++) {
        int ch = 2 * k + l;
        x[k] = (ch < 33) ? hp[ch] : 0.f;
    }
    // batch mean over b: same-parity butterfly within wave, then cross-wave LDS
    float mu[17];
#pragma unroll
    for (int k = 0; k < 17; k++) mu[k] = x[k];
#pragma unroll
    for (int d = 2; d < 64; d <<= 1) {
#pragma unroll
        for (int k = 0; k < 17; k++) mu[k] += __shfl_xor(mu[k], d);
    }
    if ((tid & 63) < 2) {
#pragma unroll
        for (int k = 0; k < 17; k++) wsum[wv][tid & 1][k] = mu[k];
    }
    __syncthreads();
#pragma unroll
    for (int k = 0; k < 17; k++)
        mu[k] = (wsum[0][l][k] + wsum[1][l][k] + wsum[2][l][k] + wsum[3][l][k]) * (1.f / 128.f);
    // normalize mu to hyperboloid: rd = rsqrt(max(mu0^2 - sum_sp, eps))
    float a0 = (l == 0) ? mu[0] : 0.f;
    a0 += __shfl_xor(a0, 1);        // both lanes now hold mu0 (pre-scale)
    float spp = 0.f;
#pragma unroll
    for (int k = 0; k < 17; k++) spp = fmaf(mu[k], mu[k], spp);
    if (l == 0) spp -= 2.f * mu[0] * mu[0];   // signed: -mu0^2 + rest
    spp += __shfl_xor(spp, 1);      // = -mu0^2 + sum_{i>=1} mu_i^2
    float rd = rsqrtf(fmaxf(-spp, 1e-8f));
#pragma unroll
    for (int k = 0; k < 17; k++) mu[k] *= rd;
    float mu0 = a0 * rd;
    // xin = -linner(x,mu) = x0*mu0 - sum_{i>=1} x_i*mu_i
    float pp = 0.f;
#pragma unroll
    for (int k = 0; k < 17; k++) pp = fmaf(x[k], mu[k], pp);
    if (l == 0) pp -= 2.f * x[0] * mu[0];
    pp += __shfl_xor(pp, 1);
    float xin = -pp;
    float dist = acoshf(fmaxf(xin, 1.f + 1e-7f));
    // var = mean_b dist^2
    float dq = dist * dist;
#pragma unroll
    for (int d = 2; d < 64; d <<= 1) dq += __shfl_xor(dq, d);
    if ((tid & 63) == 0) vsum[wv] = dq;
    __syncthreads();
    float var = (vsum[0] + vsum[1] + vsum[2] + vsum[3]) * (1.f / 128.f);
    // u = x - xin*mu
#pragma unroll
    for (int k = 0; k < 17; k++) x[k] = x[k] - xin * mu[k];
    // lu = linner(u,u) = -u0^2 + sum u_i^2
    float lup = 0.f;
#pragma unroll
    for (int k = 0; k < 17; k++) lup = fmaf(x[k], x[k], lup);
    if (l == 0) lup -= 2.f * x[0] * x[0];
    lup += __shfl_xor(lup, 1);
    float f = dist * rsqrtf(fmaxf(lup, 1e-8f));
#pragma unroll
    for (int k = 0; k < 17; k++) x[k] *= f;     // x = v
    float v0 = (l == 0) ? x[0] : 0.f;
    v0 += __shfl_xor(v0, 1);
    float corr = -v0 / (1.f + mu0);
#pragma unroll
    for (int k = 0; k < 17; k++) x[k] = fmaf(corr, mu[k], x[k]);
    if (l == 0) x[0] += corr;        // + corr * o
    float scb = bs[w] * rsqrtf(var + 1e-5f);
#pragma unroll
    for (int k = 0; k < 17; k++) x[k] *= scb;
    // nn = linner(v,v)
    float nnp = 0.f;
#pragma unroll
    for (int k = 0; k < 17; k++) nnp = fmaf(x[k], x[k], nnp);
    if (l == 0) nnp -= 2.f * x[0] * x[0];
    nnp += __shfl_xor(nnp, 1);
    float n = sqrtf(fmaxf(nnp, 1e-9f));
    float shn = sinhf(n) / n;
    // elu(space) + sum of squares
    float e[17];
#pragma unroll
    for (int k = 0; k < 17; k++) e[k] = elu_fast(shn * x[k]);
    float sgp = 0.f;
#pragma unroll
    for (int k = 0; k < 17; k++) sgp = fmaf(e[k], e[k], sgp);
    if (l == 0) sgp -= e[0] * e[0];  // exclude time channel
    sgp += __shfl_xor(sgp, 1);
    float g0 = sqrtf(1.f + sgp);
    float* gp = G + ((size_t)w * BB + b) * 33;
#pragma unroll
    for (int k = 0; k < 17; k++) {
        int ch = 2 * k + l;
        if (ch >= 1 && ch < 33) gp[ch] = e[k];
    }
    if (l == 0) gp[0] = g0;
}

// ---- lorentz avgpool(4) + flatten -> feats + qsq ----
__global__ __launch_bounds__(256) void k_pool(
        const float* __restrict__ G, float* __restrict__ outp,
        float* __restrict__ qsq) {
    int item = blockIdx.x * 256 + threadIdx.x;  // 16384 = 128wp*128b
    int wp = item >> 7, b = item & 127;
    float avg[33];
#pragma unroll
    for (int ch = 0; ch < 33; ch++) avg[ch] = 0.f;
    for (int j = 0; j < 4; j++) {
        const float* gp = G + ((size_t)(wp * 4 + j) * BB + b) * 33;
#pragma unroll
        for (int ch = 0; ch < 33; ch++) avg[ch] += gp[ch];
    }
#pragma unroll
    for (int ch = 0; ch < 33; ch++) avg[ch] *= 0.25f;
    float sp2 = 0.f;
#pragma unroll
    for (int i = 1; i < 33; i++) sp2 = fmaf(avg[i], avg[i], sp2);
    float lnr = avg[0] * avg[0] - sp2;
    float rd2 = rsqrtf(fmaxf(lnr, 1e-8f));
    float q0 = avg[0] * rd2;
    float* fb = outp + 512 + (size_t)b * 4097;
#pragma unroll
    for (int i = 1; i < 33; i++) fb[1 + wp * 32 + (i - 1)] = avg[i] * rd2;
    qsq[b * 128 + wp] = q0 * q0;
}

// ---- merged: tnew + mlr prep + mlr logits ----
__global__ __launch_bounds__(256) void k_mlr2(
        const float* __restrict__ qsq, const float* __restrict__ z,
        const float* __restrict__ a, float* __restrict__ outp) {
    int b = blockIdx.x, tid = threadIdx.x;
    __shared__ float red[4][8];
    __shared__ float tnsh;
    if (tid < 64) {
        float s = qsq[b * 128 + tid] + qsq[b * 128 + 64 + tid];
#pragma unroll
        for (int d = 1; d < 64; d <<= 1) s += __shfl_xor(s, d);
        if (tid == 0) tnsh = sqrtf(fmaxf(s - 127.f, 1e-8f));
    }
    __syncthreads();
    float tn = tnsh;
    const float* fs = outp + 512 + (size_t)b * 4097 + 1;
    float sdot[4] = {0.f, 0.f, 0.f, 0.f}, sq[4] = {0.f, 0.f, 0.f, 0.f};
    for (int i = tid * 4; i < FEAT; i += 1024) {
        float f0 = fs[i], f1 = fs[i + 1], f2 = fs[i + 2], f3 = fs[i + 3];
#pragma unroll
        for (int c = 0; c < 4; c++) {
            float4 zv = *(const float4*)(z + c * FEAT + i);
            sdot[c] = fmaf(f0, zv.x, sdot[c]); sdot[c] = fmaf(f1, zv.y, sdot[c]);
            sdot[c] = fmaf(f2, zv.z, sdot[c]); sdot[c] = fmaf(f3, zv.w, sdot[c]);
            sq[c] = fmaf(zv.x, zv.x, sq[c]); sq[c] = fmaf(zv.y, zv.y, sq[c]);
            sq[c] = fmaf(zv.z, zv.z, sq[c]); sq[c] = fmaf(zv.w, zv.w, sq[c]);
        }
    }
#pragma unroll
    for (int d = 1; d < 64; d <<= 1) {
#pragma unroll
        for (int c = 0; c < 4; c++) {
            sdot[c] += __shfl_xor(sdot[c], d);
            sq[c]   += __shfl_xor(sq[c], d);
        }
    }
    int wv = tid >> 6;
    if ((tid & 63) == 0) {
#pragma unroll
        for (int c = 0; c < 4; c++) { red[wv][c] = sdot[c]; red[wv][4 + c] = sq[c]; }
    }
    __syncthreads();
    if (tid == 0) {
        outp[512 + (size_t)b * 4097] = tn;
#pragma unroll
        for (int c = 0; c < 4; c++) {
            float dot = red[0][c] + red[1][c] + red[2][c] + red[3][c];
            float qz  = red[0][4 + c] + red[1][4 + c] + red[2][4 + c] + red[3][4 + c];
            float nz = sqrtf(qz);
            float ca = coshf(a[c]), sa = sinhf(a[c]);
            float wt = sa * nz;
            float cb = ca * nz;
            float bb = sqrtf(fmaxf(cb * cb - wt * wt, 1e-8f));
            float alpha = fmaf(-tn, wt, ca * dot);
            float d = fabsf(asinhf(alpha / bb));
            float sg = (alpha > 0.f) ? 1.f : ((alpha < 0.f) ? -1.f : 0.f);
            outp[b * 4 + c] = sg * bb * d;
        }
    }
}

extern "C" void kernel_launch(void* const* d_in, const int* in_sizes, int n_in,
                              void* d_out, int out_size, void* d_ws, size_t ws_size,
                              hipStream_t stream) {
    const float* in   = (const float*)d_in[0];
    const float* w1   = (const float*)d_in[2];
    const float* g1   = (const float*)d_in[3];
    const float* w2   = (const float*)d_in[5];
    const float* g2   = (const float*)d_in[6];
    const float* b2   = (const float*)d_in[7];
    const float* ew   = (const float*)d_in[8];
    const float* lc1  = (const float*)d_in[9];
    const float* bs   = (const float*)d_in[10];
    const float* mlra = (const float*)d_in[11];
    const float* mlrz = (const float*)d_in[12];
    float* out = (float*)d_out;
    float* ws = (float*)d_ws;

    unsigned short* P  = (unsigned short*)(ws + OFF_P);
    unsigned short* X2 = (unsigned short*)(ws + OFF_X2);
    float* PSUM = ws + OFF_PSUM;
    float* PSQ  = ws + OFF_PSQ;
    float* SS   = ws + OFF_SS;
    float* H    = ws + OFF_H;
    float* QSQ  = ws + OFF_QSQ;
    float* G    = ws + OFF_G;

    k_p<<<dim3(8, 128), 256, 0, stream>>>(in, w2, P);
    k_cs<<<dim3(8, 128), 256, 0, stream>>>(P, w1, g1, X2, PSUM, PSQ);
    k_bn2fin<<<32, 64, 0, stream>>>(PSUM, PSQ, g2, b2, SS);
    k_mid<<<dim3(8, 128), 256, 0, stream>>>(X2, SS, ew, lc1, H);
    k_tail2<<<512, 256, 0, stream>>>(H, bs, G);
    k_pool<<<64, 256, 0, stream>>>(G, out, QSQ);
    k_mlr2<<<128, 256, 0, stream>>>(QSQ, mlrz, mlra, out);
}